// Round 18
// baseline (71.243 us; speedup 1.0000x reference)
//
#include <hip/hip_runtime.h>
#include <hip/hip_bf16.h>
#include <math.h>

#define S_LEN 1024
#define DH 64
#define NB 2
#define NHQ 32
#define NHKV 8
#define NHEADS (NB*NHKV)      // 16 kv-head planes
#define NTILE 16              // S/64
#define NTRI 136              // 16*17/2 lower-tri tiles
#define NEG_INF -1e30f
#define LOG2E 1.44269504088896340736f

using bf16x8 = __attribute__((ext_vector_type(8))) __bf16;
using f32x4  = __attribute__((ext_vector_type(4))) float;
using ushort4_t = __attribute__((ext_vector_type(4))) unsigned short;

__device__ inline unsigned short f2bf(float f){
  unsigned int u = __float_as_uint(f);
  unsigned int r = (u + 0x7FFFu + ((u >> 16) & 1u)) >> 16;
  return (unsigned short)r;
}
// hardware RNE f32->bf16 (single cvt inst on gfx950)
__device__ inline unsigned short f2bf_hw(float f){
  return __builtin_bit_cast(unsigned short, __float2bfloat16(f));
}

// async global->LDS, 16B per lane, wave-uniform LDS base + lane*16
__device__ inline void gload16(const void* g, void* l){
  __builtin_amdgcn_global_load_lds(
      (const __attribute__((address_space(1))) void*)g,
      (__attribute__((address_space(3))) void*)l, 16, 0, 0);
}

// ---------------- kernel 1 (fused prep, vectorized): q|gates|k-norm|v-transpose ----------
__global__ __launch_bounds__(256) void k_prep(const float* __restrict__ q,
                                              const float* __restrict__ k,
                                              const float* __restrict__ v,
                                              const float* __restrict__ src,
                                              const float* __restrict__ dest,
                                              unsigned short* __restrict__ qb,
                                              unsigned short* __restrict__ knb,
                                              unsigned short* __restrict__ vT,
                                              float* __restrict__ sg,
                                              float* __restrict__ dg){
  __shared__ float tile[64][65];
  int bid = blockIdx.x;
  if (bid < 4096){
    int base = (bid*256 + threadIdx.x)*4;
    float4 qv = *(const float4*)(q + base);
    ushort4_t o;
    o[0] = f2bf_hw(qv.x*LOG2E); o[1] = f2bf_hw(qv.y*LOG2E);
    o[2] = f2bf_hw(qv.z*LOG2E); o[3] = f2bf_hw(qv.w*LOG2E);
    *(ushort4_t*)(qb + base) = o;
  } else if (bid < 4128){
    int e = ((bid - 4096)*256 + threadIdx.x)*4;     // over 32768 gate elems
    if (e < NHEADS*S_LEN){
      float4 dv = *(const float4*)(dest + e);
      float4 og;
      #pragma unroll
      for (int i = 0; i < 4; ++i){
        float x = (i==0)?dv.x:(i==1)?dv.y:(i==2)?dv.z:dv.w;
        float s = 1.f/(1.f + __expf(-x));
        float g = (s > 0.f) ? exp2f(log2f(s)*(1.f/3.f)) : 0.f;
        if (i==0) og.x=g; else if (i==1) og.y=g; else if (i==2) og.z=g; else og.w=g;
      }
      *(float4*)(dg + e) = og;
    } else {
      int e2 = e - NHEADS*S_LEN;
      float4 sv = *(const float4*)(src + e2);
      float4 og;
      #pragma unroll
      for (int i = 0; i < 4; ++i){
        float x = (i==0)?sv.x:(i==1)?sv.y:(i==2)?sv.z:sv.w;
        float s = 1.f/(1.f + __expf(-x));
        float g = (s > 0.f) ? exp2f(log2f(s)*(1.f/3.f)) : 0.f;
        if (i==0) og.x=g; else if (i==1) og.y=g; else if (i==2) og.z=g; else og.w=g;
      }
      *(float4*)(sg + e2) = og;
    }
  } else if (bid < 8224){
    int row  = (bid - 4128)*4 + (threadIdx.x >> 6);
    int lane = threadIdx.x & 63;
    size_t idx = (size_t)row*DH + lane;
    float x = k[idx];
    float ss = x*x;
    #pragma unroll
    for (int off = 32; off > 0; off >>= 1) ss += __shfl_xor(ss, off);
    float r = x / (sqrtf(ss) + 1e-6f);
    knb[idx] = f2bf(r);
  } else {
    int vb = bid - 8224;
    int bh = vb >> 4;
    int jt = vb & 15;
    int j0 = jt*64;
    int tid = threadIdx.x;
    int c = tid & 63, r4 = tid >> 6;
    const float* vbp = v + ((size_t)bh << 16);
    #pragma unroll
    for (int p = 0; p < 16; ++p){
      int j = p*4 + r4;
      tile[j][c] = vbp[(size_t)(j0 + j)*DH + c];
    }
    __syncthreads();
    unsigned short* ob = vT + ((size_t)bh << 16);
    #pragma unroll
    for (int p = 0; p < 16; ++p){
      int dd = p*4 + r4;
      ob[(size_t)dd*S_LEN + j0 + c] = f2bf_hw(tile[c][dd]);
    }
  }
}

// ---------------- kernel 2: T16 column sums of log2-decay (bf16 dot, LDS-staged) ---------
__global__ __launch_bounds__(256) void k_t16(const unsigned short* __restrict__ knh,
                                             const float* __restrict__ dg,
                                             const float* __restrict__ sg,
                                             float* __restrict__ T16){
  __shared__ unsigned short Ah[4096], Bh[4096];   // 16 KB
  int head = blockIdx.x / NTRI;
  int t    = blockIdx.x % NTRI;
  int ti = 0;
  while ((ti+1)*(ti+2)/2 <= t) ti++;
  int tj = t - ti*(ti+1)/2;
  int i0 = ti*64, j0 = tj*64;
  const unsigned short* Hp = knh + (size_t)head*S_LEN*DH;
  int w = threadIdx.x >> 6, lane = threadIdx.x & 63;
  int g16 = lane >> 4, l16 = lane & 15;

  // staging: wave w covers chunks w and w+4 of each 8KB array (1KB per gload16)
  int rsub = lane >> 3;
  int cisw = ((lane & 7) ^ rsub) * 8;
  int s0 = (w*8 + rsub)*64   + cisw;     // element offset in a 64x64 tile
  int s1 = ((w+4)*8 + rsub)*64 + cisw;
  int l0 = w*512, l1 = (w+4)*512;
  {
    const unsigned short* ha = Hp + (size_t)i0*DH;
    gload16(ha + s0, Ah + l0);  gload16(ha + s1, Ah + l1);
    if (ti != tj){
      const unsigned short* hb = Hp + (size_t)j0*DH;
      gload16(hb + s0, Bh + l0);  gload16(hb + s1, Bh + l1);
    }
  }
  __syncthreads();
  const unsigned short* bhp = (ti == tj) ? Ah : Bh;

  // swizzled fragment offsets: row = (group)*16 + l16, chunk (kk*4+g16)^(l16&7)
  int c0 = g16 ^ (l16 & 7);
  int e0 = l16*64 + c0*8;
  int e1 = l16*64 + (c0 ^ 4)*8;

  bf16x8 ah[2];
  ah[0] = *(const bf16x8*)(Ah + w*1024 + e0);
  ah[1] = *(const bf16x8*)(Ah + w*1024 + e1);

  f32x4 sc[4];
  #pragma unroll
  for (int n = 0; n < 4; ++n) sc[n] = (f32x4){0.f,0.f,0.f,0.f};
  #pragma unroll
  for (int n = 0; n < 4; ++n){
    bf16x8 bh0 = *(const bf16x8*)(bhp + n*1024 + e0);
    bf16x8 bh1 = *(const bf16x8*)(bhp + n*1024 + e1);
    sc[n] = __builtin_amdgcn_mfma_f32_16x16x32_bf16(ah[0], bh0, sc[n], 0, 0, 0);
    sc[n] = __builtin_amdgcn_mfma_f32_16x16x32_bf16(ah[1], bh1, sc[n], 0, 0, 0);
  }

  float dgv[4], sgv[4];
  #pragma unroll
  for (int r = 0; r < 4; ++r) dgv[r] = dg[head*S_LEN + i0 + w*16 + g16*4 + r];
  #pragma unroll
  for (int n = 0; n < 4; ++n) sgv[n] = sg[head*S_LEN + j0 + n*16 + l16];

  float tot[4];
  #pragma unroll
  for (int n = 0; n < 4; ++n){
    float s = 0.f;
    #pragma unroll
    for (int r = 0; r < 4; ++r){
      int gi = i0 + w*16 + g16*4 + r;
      int gj = j0 + n*16 + l16;
      float x = sc[n][r];
      float aff = (x > 0.f) ? exp2f(__log2f(x)*(2.f/3.f)) : 0.f;
      aff *= dgv[r]*sgv[n];
      float ld = __log2f(1.f - fminf(aff, 1.0f - 1e-6f));   // log2 domain
      s += (gi > gj) ? ld : 0.f;
    }
    tot[n] = s;
  }
  float wt[4];
  #pragma unroll
  for (int n = 0; n < 4; ++n){
    float t0 = __shfl(tot[n], l16);
    float t1 = __shfl(tot[n], 16 + l16);
    float t2 = __shfl(tot[n], 32 + l16);
    float t3 = __shfl(tot[n], 48 + l16);
    wt[n] = t0 + t1 + t2 + t3;
  }
  float sel = (g16 == 0) ? wt[0] : (g16 == 1) ? wt[1] : (g16 == 2) ? wt[2] : wt[3];
  T16[((size_t)head*64 + ti*4 + w)*S_LEN + j0 + g16*16 + l16] = sel;
}

// ---------------- kernel 3: exclusive scan over 16-row groups -> Cpre16 (4x parallel) ----
__global__ __launch_bounds__(256) void k_cpre16(const float* __restrict__ T16,
                                                float* __restrict__ Cpre16){
  __shared__ float tot[4][64];
  int head = blockIdx.x >> 4;
  int cb   = blockIdx.x & 15;
  int c    = threadIdx.x >> 6;          // gg-chunk (16 gg each)
  int ci   = threadIdx.x & 63;
  int col  = cb*64 + ci;
  int tjc  = cb;                        // col >> 6
  float loc[16];
  float run = 0.f;
  #pragma unroll
  for (int i = 0; i < 16; ++i){
    int gg = c*16 + i;
    loc[i] = run;
    if ((gg >> 2) >= tjc) run += T16[((size_t)head*64 + gg)*S_LEN + col];
  }
  tot[c][ci] = run;
  __syncthreads();
  float base = 0.f;
  #pragma unroll
  for (int cc = 0; cc < 3; ++cc)
    if (cc < c) base += tot[cc][ci];
  #pragma unroll
  for (int i = 0; i < 16; ++i){
    int gg = c*16 + i;
    Cpre16[((size_t)head*64 + gg)*S_LEN + col] = base + loc[i];
  }
}

// ---------------- kernel 4: fused flash attention, 40KB LDS, natural 4 blocks/CU ---------
// r12's correctness-verified structure + r17's bf16-only bias, WITHOUT a launch-bounds
// cap (the r8/r12 spill cause). K SINGLE-buffered: consumed at iter top by QK; barrier B
// right after QK, then STAGE_K(jt+1) overwrites it hidden under softmax+PV. V double-
// buffered (staged at top). biasT [2][64][16] XOR-swizzled. LDS = 8+16+8+8 = 40KB exactly
// -> 4 blocks/CU if VGPR<=128 (currently 76). Tripwires: WRITE_SIZE 16384, VGPR<130.
__global__ __launch_bounds__(256, 3) void k_attn(const unsigned short* __restrict__ qb,
                                              const unsigned short* __restrict__ knb,
                                              const unsigned short* __restrict__ vT,
                                              const float* __restrict__ Cpre16,
                                              const float* __restrict__ dg,
                                              const float* __restrict__ sg,
                                              float* __restrict__ out){
  __shared__ unsigned short kts[4096];      // single buffer [64 j-rows][64 d], swizzled
  __shared__ unsigned short vts[2][4096];   // [buf][64 dd][64 j] bf16, swizzled
  __shared__ unsigned short plds[4096];     // [4 waves][16 rows][64 cols] bf16, wave-private
  __shared__ float biasT[2][64][16];        // col-major bias, XOR-swizzled rows (8 KB)

  int xcd   = blockIdx.x & 7;
  int inner = blockIdx.x >> 3;              // 0..127
  int kv    = (xcd << 1) | (inner & 1);     // 0..15
  int i16   = 63 - (inner >> 1);            // heavy first (r7 decode)
  int w     = threadIdx.x >> 6;
  int lane  = threadIdx.x & 63;
  int g16 = lane >> 4, l16 = lane & 15;
  int i0   = i16*16;
  int njt  = (i16 >> 2) + 1;
  int head = kv;
  int b = kv >> 3, gh = kv & 7;
  int bh = b*32 + gh*4 + w;

  const unsigned short* Kp = knb + (size_t)head*S_LEN*DH;
  const unsigned short* Vp = vT  + (size_t)head*DH*S_LEN;
  const unsigned short* Qp = qb  + ((size_t)bh*S_LEN + i0)*DH;
  const float*          Cp = Cpre16 + ((size_t)head*64 + i16)*S_LEN;

  // staging addressing: linear LDS dest + inverse-swizzled global src
  int rsub = lane >> 3;
  int cisw = ((lane & 7) ^ rsub) * 8;
  int kg0 = (w*8 + rsub)*64   + cisw;
  int kg1 = ((w+4)*8 + rsub)*64 + cisw;
  int vg0 = (w*8 + rsub)*1024 + cisw;
  int vg1 = ((w+4)*8 + rsub)*1024 + cisw;
  int kl0 = w*512;
  int kl1 = (w+4)*512;

  // fragment read offsets: row = n*16+l16, chunk (kk*4+g16)^(l16&7)
  int c0 = g16 ^ (l16 & 7);
  int e0 = l16*64 + c0*8;
  int e1 = l16*64 + (c0 ^ 4)*8;
  int hi = l16 >> 3, lo = l16 & 7;
  unsigned short* pw = plds + w*1024;
  int bsw = (g16 ^ (l16 & 3)) << 2;         // biasT XOR-swizzled row-word base

  // precomputed P-store pointers (loop-invariant; static indexing only)
  unsigned short* pp[16];
  #pragma unroll
  for (int n = 0; n < 4; ++n)
    #pragma unroll
    for (int r = 0; r < 4; ++r){
      int row = g16*4 + r;
      pp[n*4 + r] = pw + row*64 + (((2*n + hi) ^ (row & 7))*8) + lo;
    }

  // Q fragments (pre-scaled by log2e) + K A-fragments (i-rows) + row gates
  bf16x8 aq[2];
  aq[0] = *(const bf16x8*)(Qp + (size_t)l16*DH + g16*8);
  aq[1] = *(const bf16x8*)(Qp + (size_t)l16*DH + 32 + g16*8);
  bf16x8 ahK[2];
  {
    size_t ro = (size_t)(i0 + l16)*DH + g16*8;
    ahK[0] = *(const bf16x8*)(Kp + ro);
    ahK[1] = *(const bf16x8*)(Kp + ro + 32);
  }
  float dgw[4];
  #pragma unroll
  for (int r = 0; r < 4; ++r) dgw[r] = dg[head*S_LEN + i0 + g16*4 + r];

  auto STAGE_K = [&](int jtile){
    const unsigned short* ks = Kp + (size_t)jtile*(64*DH);
    gload16(ks + kg0, kts + kl0);
    gload16(ks + kg1, kts + kl1);
  };
  auto STAGE_V = [&](int bb, int jtile){
    const unsigned short* vs = Vp + (size_t)jtile*64;
    gload16(vs + vg0, &vts[bb][kl0]);
    gload16(vs + vg1, &vts[bb][kl1]);
  };

  // bias tile for jt (own 16-col group), from GLOBAL K rows -> biasT[buf] (log2 units)
  auto BIAS = [&](int jt, int buf){
    int colw = jt*64 + (w << 4) + l16;
    float sgv_o = sg[head*S_LEN + colw];
    float cp_o  = Cp[colw];
    const unsigned short* hrow = Kp + (size_t)colw*DH;
    bf16x8 bh0 = *(const bf16x8*)(hrow + g16*8);
    bf16x8 bh1 = *(const bf16x8*)(hrow + 32 + g16*8);
    f32x4 bd = (f32x4){0.f,0.f,0.f,0.f};
    bd = __builtin_amdgcn_mfma_f32_16x16x32_bf16(ahK[0], bh0, bd, 0, 0, 0);
    bd = __builtin_amdgcn_mfma_f32_16x16x32_bf16(ahK[1], bh1, bd, 0, 0, 0);
    float pre[4];
    float s = 0.f;
    #pragma unroll
    for (int r = 0; r < 4; ++r){
      float x = bd[r];
      float aff = (x > 0.f) ? exp2f(__log2f(x)*(2.f/3.f)) : 0.f;
      aff *= dgw[r]*sgv_o;
      float ld = __log2f(1.f - fminf(aff, 1.0f - 1e-6f));
      ld = ((i0 + g16*4 + r) > colw) ? ld : 0.f;
      pre[r] = s; s += ld;
    }
    float t0 = __shfl(s, l16);
    float t1 = __shfl(s, 16 + l16);
    float t2 = __shfl(s, 32 + l16);
    float offg = (g16 > 0 ? t0 : 0.f) + (g16 > 1 ? t1 : 0.f) + (g16 > 2 ? t2 : 0.f);
    f32x4 st;
    #pragma unroll
    for (int r = 0; r < 4; ++r) st[r] = cp_o + offg + pre[r];
    // XOR-swizzled store: rows g16*4..+3 of col live at words (g16^(col&3))*4..+3
    *(f32x4*)&biasT[buf][(w << 4) + l16][bsw] = st;
  };

  f32x4 oacc[4];
  float m[4], ssum[4];
  #pragma unroll
  for (int n = 0; n < 4; ++n) oacc[n] = (f32x4){0.f,0.f,0.f,0.f};
  #pragma unroll
  for (int r = 0; r < 4; ++r){ m[r] = NEG_INF; ssum[r] = 0.f; }

  // softmax + P-store + PV (V from vts[cur] via LDS pointer)
  auto SM_PV = [&](f32x4* sc, const unsigned short* vcur){
    float mx[4];
    #pragma unroll
    for (int r = 0; r < 4; ++r)
      mx[r] = fmaxf(fmaxf(sc[0][r], sc[1][r]), fmaxf(sc[2][r], sc[3][r]));
    #pragma unroll
    for (int off = 8; off >= 1; off >>= 1)
      #pragma unroll
      for (int r = 0; r < 4; ++r)
        mx[r] = fmaxf(mx[r], __shfl_xor(mx[r], off));
    float dmax = fmaxf(fmaxf(mx[0]-m[0], mx[1]-m[1]), fmaxf(mx[2]-m[2], mx[3]-m[3]));
    if (__any(dmax > 8.f)){
      #pragma unroll
      for (int r = 0; r < 4; ++r){
        float mn = fmaxf(m[r], mx[r]);
        float scale = exp2f(m[r] - mn);
        m[r] = mn;
        ssum[r] *= scale;
        #pragma unroll
        for (int n = 0; n < 4; ++n) oacc[n][r] *= scale;
      }
    }
    #pragma unroll
    for (int n = 0; n < 4; ++n){
      #pragma unroll
      for (int r = 0; r < 4; ++r){
        float pv = exp2f(sc[n][r] - m[r]);     // raw v_exp_f32; bounded by 2^8
        ssum[r] += pv;
        *pp[n*4 + r] = f2bf_hw(pv);            // precomputed LDS address
      }
    }
    bf16x8 pa0 = *(const bf16x8*)(pw + e0);
    bf16x8 pa1 = *(const bf16x8*)(pw + e1);
    __builtin_amdgcn_s_setprio(1);
    #pragma unroll
    for (int n = 0; n < 4; ++n){
      bf16x8 bv = *(const bf16x8*)(vcur + n*1024 + e0);
      oacc[n] = __builtin_amdgcn_mfma_f32_16x16x32_bf16(pa0, bv, oacc[n], 0, 0, 0);
    }
    #pragma unroll
    for (int n = 0; n < 4; ++n){
      bf16x8 bv = *(const bf16x8*)(vcur + n*1024 + e1);
      oacc[n] = __builtin_amdgcn_mfma_f32_16x16x32_bf16(pa1, bv, oacc[n], 0, 0, 0);
    }
    __builtin_amdgcn_s_setprio(0);
  };

  // prologue: stage K(0), V(0), bias(0); one barrier makes all visible
  STAGE_K(0);
  STAGE_V(0, 0);
  BIAS(0, 0);
  __syncthreads();

  int cur = 0, nb = 0;
  for (int jt = 0; jt < njt; ++jt){
    bool last = (jt == njt - 1);
    const unsigned short* vcur = &vts[cur][0];

    if (!last) STAGE_V(cur ^ 1, jt + 1);   // async, full iteration to hide

    // QK^T from single-buffered kts (log2-scaled logits)
    f32x4 sc[4];
    #pragma unroll
    for (int n = 0; n < 4; ++n) sc[n] = (f32x4){0.f,0.f,0.f,0.f};
    __builtin_amdgcn_s_setprio(1);
    #pragma unroll
    for (int n = 0; n < 4; ++n){
      bf16x8 bk0 = *(const bf16x8*)(kts + n*1024 + e0);
      bf16x8 bk1 = *(const bf16x8*)(kts + n*1024 + e1);
      sc[n] = __builtin_amdgcn_mfma_f32_16x16x32_bf16(aq[0], bk0, sc[n], 0, 0, 0);
      sc[n] = __builtin_amdgcn_mfma_f32_16x16x32_bf16(aq[1], bk1, sc[n], 0, 0, 0);
    }
    __builtin_amdgcn_s_setprio(0);

    __syncthreads();                       // barrier B: all waves' kts reads complete

    if (!last){
      STAGE_K(jt + 1);                     // overwrite kts; hidden under softmax+PV
      BIAS(jt + 1, nb ^ 1);                // off critical path, double-buffered
    }

    // add current bias (4x ds_read_b128, swizzled); causal mask on last tile
    if (last){
      int lim = (i16 & 3) << 4;
      #pragma unroll
      for (int n = 0; n < 4; ++n){
        f32x4 bvv = *(const f32x4*)&biasT[nb][n*16 + l16][bsw];
        #pragma unroll
        for (int r = 0; r < 4; ++r){
          int row = g16*4 + r;
          int col = n*16 + l16;
          sc[n][r] = (col <= lim + row) ? (sc[n][r] + bvv[r]) : NEG_INF;
        }
      }
    } else {
      #pragma unroll
      for (int n = 0; n < 4; ++n){
        f32x4 bvv = *(const f32x4*)&biasT[nb][n*16 + l16][bsw];
        #pragma unroll
        for (int r = 0; r < 4; ++r) sc[n][r] += bvv[r];
      }
    }

    SM_PV(sc, vcur);

    __syncthreads();       // barrier A: drains K/V stages, swaps vts/biasT
    cur ^= 1; nb ^= 1;
  }

  // epilogue
  #pragma unroll
  for (int off = 8; off >= 1; off >>= 1)
    #pragma unroll
    for (int r = 0; r < 4; ++r) ssum[r] += __shfl_xor(ssum[r], off);
  float* Op = out + ((size_t)bh*S_LEN + i0)*DH;
  #pragma unroll
  for (int n = 0; n < 4; ++n)
    #pragma unroll
    for (int r = 0; r < 4; ++r)
      Op[(size_t)(g16*4 + r)*DH + n*16 + l16] = oacc[n][r] / ssum[r];
}

extern "C" void kernel_launch(void* const* d_in, const int* in_sizes, int n_in,
                              void* d_out, int out_size, void* d_ws, size_t ws_size,
                              hipStream_t stream){
  const float* q    = (const float*)d_in[0];
  const float* k    = (const float*)d_in[1];
  const float* v    = (const float*)d_in[2];
  const float* src  = (const float*)d_in[3];
  const float* dest = (const float*)d_in[4];
  float* out = (float*)d_out;

  char* w = (char*)d_ws;
  unsigned short* qb   = (unsigned short*)w;                          // 8 MB
  unsigned short* knb  = (unsigned short*)(w + (size_t)(8u  << 20));  // 2 MB
  unsigned short* vT   = (unsigned short*)(w + (size_t)(10u << 20));  // 2 MB
  float*          dg   = (float*)(w + (size_t)(12u << 20));           // 64 KB
  float*          sg   = (float*)(w + (size_t)(12u << 20) + 65536);   // 64 KB
  float*          T16  = (float*)(w + (size_t)(13u << 20));           // 4 MB
  float*          Cpre = (float*)(w + (size_t)(17u << 20));           // 4 MB

  k_prep   <<<dim3(8480), dim3(256), 0, stream>>>(q, k, v, src, dest, qb, knb, vT, sg, dg);
  k_t16    <<<dim3(NHEADS*NTRI), dim3(256), 0, stream>>>(knb, dg, sg, T16);
  k_cpre16 <<<dim3(NHEADS*16), dim3(256), 0, stream>>>(T16, Cpre);
  k_attn   <<<dim3(NB*NHKV*64), dim3(256), 0, stream>>>(qb, knb, vT, Cpre, dg, sg, out);
}

// Round 19
// 70.886 us; speedup vs baseline: 1.0050x; 1.0050x over previous
//
#include <hip/hip_runtime.h>
#include <hip/hip_bf16.h>
#include <math.h>

#define S_LEN 1024
#define DH 64
#define NB 2
#define NHQ 32
#define NHKV 8
#define NHEADS (NB*NHKV)      // 16 kv-head planes
#define NTILE 16              // S/64
#define NTRI 136              // 16*17/2 lower-tri tiles
#define NEG_INF -1e30f
#define LOG2E 1.44269504088896340736f

using bf16x8 = __attribute__((ext_vector_type(8))) __bf16;
using f32x4  = __attribute__((ext_vector_type(4))) float;
using ushort4_t = __attribute__((ext_vector_type(4))) unsigned short;

__device__ inline unsigned short f2bf(float f){
  unsigned int u = __float_as_uint(f);
  unsigned int r = (u + 0x7FFFu + ((u >> 16) & 1u)) >> 16;
  return (unsigned short)r;
}
// hardware RNE f32->bf16 (single cvt inst on gfx950)
__device__ inline unsigned short f2bf_hw(float f){
  return __builtin_bit_cast(unsigned short, __float2bfloat16(f));
}

// async global->LDS, 16B per lane, wave-uniform LDS base + lane*16
__device__ inline void gload16(const void* g, void* l){
  __builtin_amdgcn_global_load_lds(
      (const __attribute__((address_space(1))) void*)g,
      (__attribute__((address_space(3))) void*)l, 16, 0, 0);
}

// ---------------- kernel 1 (fused prep, vectorized): q|gates|k-norm|v-transpose ----------
__global__ __launch_bounds__(256) void k_prep(const float* __restrict__ q,
                                              const float* __restrict__ k,
                                              const float* __restrict__ v,
                                              const float* __restrict__ src,
                                              const float* __restrict__ dest,
                                              unsigned short* __restrict__ qb,
                                              unsigned short* __restrict__ knb,
                                              unsigned short* __restrict__ vT,
                                              float* __restrict__ sg,
                                              float* __restrict__ dg){
  __shared__ float tile[64][65];
  int bid = blockIdx.x;
  if (bid < 4096){
    int base = (bid*256 + threadIdx.x)*4;
    float4 qv = *(const float4*)(q + base);
    ushort4_t o;
    o[0] = f2bf_hw(qv.x*LOG2E); o[1] = f2bf_hw(qv.y*LOG2E);
    o[2] = f2bf_hw(qv.z*LOG2E); o[3] = f2bf_hw(qv.w*LOG2E);
    *(ushort4_t*)(qb + base) = o;
  } else if (bid < 4128){
    int e = ((bid - 4096)*256 + threadIdx.x)*4;     // over 32768 gate elems
    if (e < NHEADS*S_LEN){
      float4 dv = *(const float4*)(dest + e);
      float4 og;
      #pragma unroll
      for (int i = 0; i < 4; ++i){
        float x = (i==0)?dv.x:(i==1)?dv.y:(i==2)?dv.z:dv.w;
        float s = 1.f/(1.f + __expf(-x));
        float g = (s > 0.f) ? exp2f(log2f(s)*(1.f/3.f)) : 0.f;
        if (i==0) og.x=g; else if (i==1) og.y=g; else if (i==2) og.z=g; else og.w=g;
      }
      *(float4*)(dg + e) = og;
    } else {
      int e2 = e - NHEADS*S_LEN;
      float4 sv = *(const float4*)(src + e2);
      float4 og;
      #pragma unroll
      for (int i = 0; i < 4; ++i){
        float x = (i==0)?sv.x:(i==1)?sv.y:(i==2)?sv.z:sv.w;
        float s = 1.f/(1.f + __expf(-x));
        float g = (s > 0.f) ? exp2f(log2f(s)*(1.f/3.f)) : 0.f;
        if (i==0) og.x=g; else if (i==1) og.y=g; else if (i==2) og.z=g; else og.w=g;
      }
      *(float4*)(sg + e2) = og;
    }
  } else if (bid < 8224){
    int row  = (bid - 4128)*4 + (threadIdx.x >> 6);
    int lane = threadIdx.x & 63;
    size_t idx = (size_t)row*DH + lane;
    float x = k[idx];
    float ss = x*x;
    #pragma unroll
    for (int off = 32; off > 0; off >>= 1) ss += __shfl_xor(ss, off);
    float r = x / (sqrtf(ss) + 1e-6f);
    knb[idx] = f2bf(r);
  } else {
    int vb = bid - 8224;
    int bh = vb >> 4;
    int jt = vb & 15;
    int j0 = jt*64;
    int tid = threadIdx.x;
    int c = tid & 63, r4 = tid >> 6;
    const float* vbp = v + ((size_t)bh << 16);
    #pragma unroll
    for (int p = 0; p < 16; ++p){
      int j = p*4 + r4;
      tile[j][c] = vbp[(size_t)(j0 + j)*DH + c];
    }
    __syncthreads();
    unsigned short* ob = vT + ((size_t)bh << 16);
    #pragma unroll
    for (int p = 0; p < 16; ++p){
      int dd = p*4 + r4;
      ob[(size_t)dd*S_LEN + j0 + c] = f2bf_hw(tile[c][dd]);
    }
  }
}

// ---------------- kernel 2: T16 column sums of log2-decay (bf16 dot, LDS-staged) ---------
__global__ __launch_bounds__(256) void k_t16(const unsigned short* __restrict__ knh,
                                             const float* __restrict__ dg,
                                             const float* __restrict__ sg,
                                             float* __restrict__ T16){
  __shared__ unsigned short Ah[4096], Bh[4096];   // 16 KB
  int head = blockIdx.x / NTRI;
  int t    = blockIdx.x % NTRI;
  int ti = 0;
  while ((ti+1)*(ti+2)/2 <= t) ti++;
  int tj = t - ti*(ti+1)/2;
  int i0 = ti*64, j0 = tj*64;
  const unsigned short* Hp = knh + (size_t)head*S_LEN*DH;
  int w = threadIdx.x >> 6, lane = threadIdx.x & 63;
  int g16 = lane >> 4, l16 = lane & 15;

  // staging: wave w covers chunks w and w+4 of each 8KB array (1KB per gload16)
  int rsub = lane >> 3;
  int cisw = ((lane & 7) ^ rsub) * 8;
  int s0 = (w*8 + rsub)*64   + cisw;     // element offset in a 64x64 tile
  int s1 = ((w+4)*8 + rsub)*64 + cisw;
  int l0 = w*512, l1 = (w+4)*512;
  {
    const unsigned short* ha = Hp + (size_t)i0*DH;
    gload16(ha + s0, Ah + l0);  gload16(ha + s1, Ah + l1);
    if (ti != tj){
      const unsigned short* hb = Hp + (size_t)j0*DH;
      gload16(hb + s0, Bh + l0);  gload16(hb + s1, Bh + l1);
    }
  }
  __syncthreads();
  const unsigned short* bhp = (ti == tj) ? Ah : Bh;

  // swizzled fragment offsets: row = (group)*16 + l16, chunk (kk*4+g16)^(l16&7)
  int c0 = g16 ^ (l16 & 7);
  int e0 = l16*64 + c0*8;
  int e1 = l16*64 + (c0 ^ 4)*8;

  bf16x8 ah[2];
  ah[0] = *(const bf16x8*)(Ah + w*1024 + e0);
  ah[1] = *(const bf16x8*)(Ah + w*1024 + e1);

  f32x4 sc[4];
  #pragma unroll
  for (int n = 0; n < 4; ++n) sc[n] = (f32x4){0.f,0.f,0.f,0.f};
  #pragma unroll
  for (int n = 0; n < 4; ++n){
    bf16x8 bh0 = *(const bf16x8*)(bhp + n*1024 + e0);
    bf16x8 bh1 = *(const bf16x8*)(bhp + n*1024 + e1);
    sc[n] = __builtin_amdgcn_mfma_f32_16x16x32_bf16(ah[0], bh0, sc[n], 0, 0, 0);
    sc[n] = __builtin_amdgcn_mfma_f32_16x16x32_bf16(ah[1], bh1, sc[n], 0, 0, 0);
  }

  float dgv[4], sgv[4];
  #pragma unroll
  for (int r = 0; r < 4; ++r) dgv[r] = dg[head*S_LEN + i0 + w*16 + g16*4 + r];
  #pragma unroll
  for (int n = 0; n < 4; ++n) sgv[n] = sg[head*S_LEN + j0 + n*16 + l16];

  float tot[4];
  #pragma unroll
  for (int n = 0; n < 4; ++n){
    float s = 0.f;
    #pragma unroll
    for (int r = 0; r < 4; ++r){
      int gi = i0 + w*16 + g16*4 + r;
      int gj = j0 + n*16 + l16;
      float x = sc[n][r];
      float aff = (x > 0.f) ? exp2f(__log2f(x)*(2.f/3.f)) : 0.f;
      aff *= dgv[r]*sgv[n];
      float ld = __log2f(1.f - fminf(aff, 1.0f - 1e-6f));   // log2 domain
      s += (gi > gj) ? ld : 0.f;
    }
    tot[n] = s;
  }
  float wt[4];
  #pragma unroll
  for (int n = 0; n < 4; ++n){
    float t0 = __shfl(tot[n], l16);
    float t1 = __shfl(tot[n], 16 + l16);
    float t2 = __shfl(tot[n], 32 + l16);
    float t3 = __shfl(tot[n], 48 + l16);
    wt[n] = t0 + t1 + t2 + t3;
  }
  float sel = (g16 == 0) ? wt[0] : (g16 == 1) ? wt[1] : (g16 == 2) ? wt[2] : wt[3];
  T16[((size_t)head*64 + ti*4 + w)*S_LEN + j0 + g16*16 + l16] = sel;
}

// ---------------- kernel 3: exclusive scan over 16-row groups -> Cpre16 (4x parallel) ----
__global__ __launch_bounds__(256) void k_cpre16(const float* __restrict__ T16,
                                                float* __restrict__ Cpre16){
  __shared__ float tot[4][64];
  int head = blockIdx.x >> 4;
  int cb   = blockIdx.x & 15;
  int c    = threadIdx.x >> 6;          // gg-chunk (16 gg each)
  int ci   = threadIdx.x & 63;
  int col  = cb*64 + ci;
  int tjc  = cb;                        // col >> 6
  float loc[16];
  float run = 0.f;
  #pragma unroll
  for (int i = 0; i < 16; ++i){
    int gg = c*16 + i;
    loc[i] = run;
    if ((gg >> 2) >= tjc) run += T16[((size_t)head*64 + gg)*S_LEN + col];
  }
  tot[c][ci] = run;
  __syncthreads();
  float base = 0.f;
  #pragma unroll
  for (int cc = 0; cc < 3; ++cc)
    if (cc < c) base += tot[cc][ci];
  #pragma unroll
  for (int i = 0; i < 16; ++i){
    int gg = c*16 + i;
    Cpre16[((size_t)head*64 + gg)*S_LEN + col] = base + loc[i];
  }
}

// ---------------- kernel 4: fused flash attention (r17 proven best, byte-identical) ------
// block = (kv-head, one 16-row i-block), 4 waves = 4 GQA q-heads. Monotone heavy-first
// decode. K/V double-buffered LDS via global_load_lds; bias for jt+1 pipelined into
// double-buffered biasT (bf16 dot — consistent with k_t16). log2-domain softmax + THR=8
// defer-rescale. Branch-free steady loop (last iter peeled), precomputed P-store ptrs.
// CLOSED families: launch_bounds(256,4) cap (r8,r12: spill), V-in-reg (r15: spill),
// 40KB/2-barrier (r18: occupancy unchanged, conflicts up, net -1%).
__global__ __launch_bounds__(256, 3) void k_attn(const unsigned short* __restrict__ qb,
                                              const unsigned short* __restrict__ knb,
                                              const unsigned short* __restrict__ vT,
                                              const float* __restrict__ Cpre16,
                                              const float* __restrict__ dg,
                                              const float* __restrict__ sg,
                                              float* __restrict__ out){
  __shared__ unsigned short kts[2][4096];   // [buf][64 j-rows][64 d] bf16, swizzled
  __shared__ unsigned short vts[2][4096];   // [buf][64 dd   ][64 j] bf16, swizzled
  __shared__ unsigned short plds[4096];     // [4 waves][16 rows][64 cols] bf16, wave-private
  __shared__ float biasT[2][64][20];        // col-major bias [buf][col][row], 80B stride

  int xcd   = blockIdx.x & 7;
  int inner = blockIdx.x >> 3;              // 0..127
  int kv    = (xcd << 1) | (inner & 1);     // 0..15
  int i16   = 63 - (inner >> 1);            // heavy first (r7 decode)
  int w     = threadIdx.x >> 6;
  int lane  = threadIdx.x & 63;
  int g16 = lane >> 4, l16 = lane & 15;
  int i0   = i16*16;
  int njt  = (i16 >> 2) + 1;
  int head = kv;
  int b = kv >> 3, gh = kv & 7;
  int bh = b*32 + gh*4 + w;

  const unsigned short* Kp = knb + (size_t)head*S_LEN*DH;
  const unsigned short* Vp = vT  + (size_t)head*DH*S_LEN;
  const unsigned short* Qp = qb  + ((size_t)bh*S_LEN + i0)*DH;
  const float*          Cp = Cpre16 + ((size_t)head*64 + i16)*S_LEN;

  // staging addressing: linear LDS dest + inverse-swizzled global src
  int rsub = lane >> 3;
  int cisw = ((lane & 7) ^ rsub) * 8;
  int kg0 = (w*8 + rsub)*64   + cisw;
  int kg1 = ((w+4)*8 + rsub)*64 + cisw;
  int vg0 = (w*8 + rsub)*1024 + cisw;
  int vg1 = ((w+4)*8 + rsub)*1024 + cisw;
  int kl0 = w*512;
  int kl1 = (w+4)*512;

  // fragment read offsets: row = n*16+l16, chunk (kk*4+g16)^(l16&7)
  int c0 = g16 ^ (l16 & 7);
  int e0 = l16*64 + c0*8;
  int e1 = l16*64 + (c0 ^ 4)*8;
  int hi = l16 >> 3, lo = l16 & 7;
  unsigned short* pw = plds + w*1024;

  // precomputed P-store pointers (loop-invariant; static indexing only)
  unsigned short* pp[16];
  #pragma unroll
  for (int n = 0; n < 4; ++n)
    #pragma unroll
    for (int r = 0; r < 4; ++r){
      int row = g16*4 + r;
      pp[n*4 + r] = pw + row*64 + (((2*n + hi) ^ (row & 7))*8) + lo;
    }

  // Q fragments (pre-scaled by log2e) + K A-fragments (i-rows) + row gates
  bf16x8 aq[2];
  aq[0] = *(const bf16x8*)(Qp + (size_t)l16*DH + g16*8);
  aq[1] = *(const bf16x8*)(Qp + (size_t)l16*DH + 32 + g16*8);
  bf16x8 ahK[2];
  {
    size_t ro = (size_t)(i0 + l16)*DH + g16*8;
    ahK[0] = *(const bf16x8*)(Kp + ro);
    ahK[1] = *(const bf16x8*)(Kp + ro + 32);
  }
  float dgw[4];
  #pragma unroll
  for (int r = 0; r < 4; ++r) dgw[r] = dg[head*S_LEN + i0 + g16*4 + r];

  auto STAGE = [&](int bb, int jtile){
    const unsigned short* ks = Kp + (size_t)jtile*(64*DH);
    const unsigned short* vs = Vp + (size_t)jtile*64;
    gload16(ks + kg0, &kts[bb][kl0]);
    gload16(ks + kg1, &kts[bb][kl1]);
    gload16(vs + vg0, &vts[bb][kl0]);
    gload16(vs + vg1, &vts[bb][kl1]);
  };

  // bias tile for jt (own 16-col group), from GLOBAL K rows -> biasT[buf] (log2 units)
  auto BIAS = [&](int jt, int buf){
    int colw = jt*64 + (w << 4) + l16;
    float sgv_o = sg[head*S_LEN + colw];
    float cp_o  = Cp[colw];
    const unsigned short* hrow = Kp + (size_t)colw*DH;
    bf16x8 bh0 = *(const bf16x8*)(hrow + g16*8);
    bf16x8 bh1 = *(const bf16x8*)(hrow + 32 + g16*8);
    f32x4 bd = (f32x4){0.f,0.f,0.f,0.f};
    bd = __builtin_amdgcn_mfma_f32_16x16x32_bf16(ahK[0], bh0, bd, 0, 0, 0);
    bd = __builtin_amdgcn_mfma_f32_16x16x32_bf16(ahK[1], bh1, bd, 0, 0, 0);
    float pre[4];
    float s = 0.f;
    #pragma unroll
    for (int r = 0; r < 4; ++r){
      float x = bd[r];
      float aff = (x > 0.f) ? exp2f(__log2f(x)*(2.f/3.f)) : 0.f;
      aff *= dgw[r]*sgv_o;
      float ld = __log2f(1.f - fminf(aff, 1.0f - 1e-6f));
      ld = ((i0 + g16*4 + r) > colw) ? ld : 0.f;
      pre[r] = s; s += ld;
    }
    float t0 = __shfl(s, l16);
    float t1 = __shfl(s, 16 + l16);
    float t2 = __shfl(s, 32 + l16);
    float offg = (g16 > 0 ? t0 : 0.f) + (g16 > 1 ? t1 : 0.f) + (g16 > 2 ? t2 : 0.f);
    f32x4 st;
    #pragma unroll
    for (int r = 0; r < 4; ++r) st[r] = cp_o + offg + pre[r];
    *(f32x4*)&biasT[buf][(w << 4) + l16][g16*4] = st;   // one ds_write_b128
  };

  f32x4 oacc[4];
  float m[4], ssum[4];
  #pragma unroll
  for (int n = 0; n < 4; ++n) oacc[n] = (f32x4){0.f,0.f,0.f,0.f};
  #pragma unroll
  for (int r = 0; r < 4; ++r){ m[r] = NEG_INF; ssum[r] = 0.f; }

  // softmax + P-store + PV (shared by steady loop and peeled last iter)
  auto SM_PV = [&](f32x4* sc, const unsigned short* vcur){
    float mx[4];
    #pragma unroll
    for (int r = 0; r < 4; ++r)
      mx[r] = fmaxf(fmaxf(sc[0][r], sc[1][r]), fmaxf(sc[2][r], sc[3][r]));
    #pragma unroll
    for (int off = 8; off >= 1; off >>= 1)
      #pragma unroll
      for (int r = 0; r < 4; ++r)
        mx[r] = fmaxf(mx[r], __shfl_xor(mx[r], off));
    float dmax = fmaxf(fmaxf(mx[0]-m[0], mx[1]-m[1]), fmaxf(mx[2]-m[2], mx[3]-m[3]));
    if (__any(dmax > 8.f)){
      #pragma unroll
      for (int r = 0; r < 4; ++r){
        float mn = fmaxf(m[r], mx[r]);
        float scale = exp2f(m[r] - mn);
        m[r] = mn;
        ssum[r] *= scale;
        #pragma unroll
        for (int n = 0; n < 4; ++n) oacc[n][r] *= scale;
      }
    }
    #pragma unroll
    for (int n = 0; n < 4; ++n){
      #pragma unroll
      for (int r = 0; r < 4; ++r){
        float pv = exp2f(sc[n][r] - m[r]);     // raw v_exp_f32; bounded by 2^8
        ssum[r] += pv;
        *pp[n*4 + r] = f2bf_hw(pv);            // precomputed LDS address
      }
    }
    bf16x8 pa0 = *(const bf16x8*)(pw + e0);
    bf16x8 pa1 = *(const bf16x8*)(pw + e1);
    __builtin_amdgcn_s_setprio(1);
    #pragma unroll
    for (int n = 0; n < 4; ++n){
      bf16x8 bv = *(const bf16x8*)(vcur + n*1024 + e0);
      oacc[n] = __builtin_amdgcn_mfma_f32_16x16x32_bf16(pa0, bv, oacc[n], 0, 0, 0);
    }
    #pragma unroll
    for (int n = 0; n < 4; ++n){
      bf16x8 bv = *(const bf16x8*)(vcur + n*1024 + e1);
      oacc[n] = __builtin_amdgcn_mfma_f32_16x16x32_bf16(pa1, bv, oacc[n], 0, 0, 0);
    }
    __builtin_amdgcn_s_setprio(0);
  };

  // prologue: stage tile 0 + bias(0); one barrier makes both visible
  STAGE(0, 0);
  BIAS(0, 0);
  __syncthreads();

  int cur = 0, nb = 0;
  // ---- steady state: branch-free body (last iteration peeled) ----
  for (int jt = 0; jt < njt - 1; ++jt){
    const unsigned short* kcur = &kts[cur][0];
    const unsigned short* vcur = &vts[cur][0];

    STAGE(cur ^ 1, jt + 1);              // async, in flight across the whole iteration

    f32x4 sc[4];
    #pragma unroll
    for (int n = 0; n < 4; ++n) sc[n] = (f32x4){0.f,0.f,0.f,0.f};
    __builtin_amdgcn_s_setprio(1);
    #pragma unroll
    for (int n = 0; n < 4; ++n){
      bf16x8 bk0 = *(const bf16x8*)(kcur + n*1024 + e0);
      bf16x8 bk1 = *(const bf16x8*)(kcur + n*1024 + e1);
      sc[n] = __builtin_amdgcn_mfma_f32_16x16x32_bf16(aq[0], bk0, sc[n], 0, 0, 0);
      sc[n] = __builtin_amdgcn_mfma_f32_16x16x32_bf16(aq[1], bk1, sc[n], 0, 0, 0);
    }
    __builtin_amdgcn_s_setprio(0);

    BIAS(jt + 1, nb ^ 1);                // off critical path, double-buffered

    #pragma unroll
    for (int n = 0; n < 4; ++n){
      f32x4 bvv = *(const f32x4*)&biasT[nb][n*16 + l16][g16*4];
      #pragma unroll
      for (int r = 0; r < 4; ++r) sc[n][r] += bvv[r];
    }

    SM_PV(sc, vcur);

    __syncthreads();                     // swaps kts/vts/biasT, drains STAGE vmcnt
    cur ^= 1; nb ^= 1;
  }

  // ---- peeled last iteration: masked bias add, no STAGE/BIAS, no trailing barrier ----
  {
    const unsigned short* kcur = &kts[cur][0];
    const unsigned short* vcur = &vts[cur][0];

    f32x4 sc[4];
    #pragma unroll
    for (int n = 0; n < 4; ++n) sc[n] = (f32x4){0.f,0.f,0.f,0.f};
    __builtin_amdgcn_s_setprio(1);
    #pragma unroll
    for (int n = 0; n < 4; ++n){
      bf16x8 bk0 = *(const bf16x8*)(kcur + n*1024 + e0);
      bf16x8 bk1 = *(const bf16x8*)(kcur + n*1024 + e1);
      sc[n] = __builtin_amdgcn_mfma_f32_16x16x32_bf16(aq[0], bk0, sc[n], 0, 0, 0);
      sc[n] = __builtin_amdgcn_mfma_f32_16x16x32_bf16(aq[1], bk1, sc[n], 0, 0, 0);
    }
    __builtin_amdgcn_s_setprio(0);

    int lim = (i16 & 3) << 4;
    #pragma unroll
    for (int n = 0; n < 4; ++n){
      f32x4 bvv = *(const f32x4*)&biasT[nb][n*16 + l16][g16*4];
      #pragma unroll
      for (int r = 0; r < 4; ++r){
        int row = g16*4 + r;
        int col = n*16 + l16;
        sc[n][r] = (col <= lim + row) ? (sc[n][r] + bvv[r]) : NEG_INF;
      }
    }

    SM_PV(sc, vcur);
  }

  // epilogue
  #pragma unroll
  for (int off = 8; off >= 1; off >>= 1)
    #pragma unroll
    for (int r = 0; r < 4; ++r) ssum[r] += __shfl_xor(ssum[r], off);
  float* Op = out + ((size_t)bh*S_LEN + i0)*DH;
  #pragma unroll
  for (int n = 0; n < 4; ++n)
    #pragma unroll
    for (int r = 0; r < 4; ++r)
      Op[(size_t)(g16*4 + r)*DH + n*16 + l16] = oacc[n][r] / ssum[r];
}

extern "C" void kernel_launch(void* const* d_in, const int* in_sizes, int n_in,
                              void* d_out, int out_size, void* d_ws, size_t ws_size,
                              hipStream_t stream){
  const float* q    = (const float*)d_in[0];
  const float* k    = (const float*)d_in[1];
  const float* v    = (const float*)d_in[2];
  const float* src  = (const float*)d_in[3];
  const float* dest = (const float*)d_in[4];
  float* out = (float*)d_out;

  char* w = (char*)d_ws;
  unsigned short* qb   = (unsigned short*)w;                          // 8 MB
  unsigned short* knb  = (unsigned short*)(w + (size_t)(8u  << 20));  // 2 MB
  unsigned short* vT   = (unsigned short*)(w + (size_t)(10u << 20));  // 2 MB
  float*          dg   = (float*)(w + (size_t)(12u << 20));           // 64 KB
  float*          sg   = (float*)(w + (size_t)(12u << 20) + 65536);   // 64 KB
  float*          T16  = (float*)(w + (size_t)(13u << 20));           // 4 MB
  float*          Cpre = (float*)(w + (size_t)(17u << 20));           // 4 MB

  k_prep   <<<dim3(8480), dim3(256), 0, stream>>>(q, k, v, src, dest, qb, knb, vT, sg, dg);
  k_t16    <<<dim3(NHEADS*NTRI), dim3(256), 0, stream>>>(knb, dg, sg, T16);
  k_cpre16 <<<dim3(NHEADS*16), dim3(256), 0, stream>>>(T16, Cpre);
  k_attn   <<<dim3(NB*NHKV*64), dim3(256), 0, stream>>>(qb, knb, vT, Cpre, dg, sg, out);
}

// Round 20
// 69.995 us; speedup vs baseline: 1.0178x; 1.0127x over previous
//
#include <hip/hip_runtime.h>
#include <hip/hip_bf16.h>
#include <math.h>

#define S_LEN 1024
#define DH 64
#define NB 2
#define NHQ 32
#define NHKV 8
#define NHEADS (NB*NHKV)      // 16 kv-head planes
#define NTILE 16              // S/64
#define NTRI 136              // 16*17/2 lower-tri tiles
#define NEG_INF -1e30f
#define LOG2E 1.44269504088896340736f

using bf16x8 = __attribute__((ext_vector_type(8))) __bf16;
using f32x4  = __attribute__((ext_vector_type(4))) float;
using ushort4_t = __attribute__((ext_vector_type(4))) unsigned short;

__device__ inline unsigned short f2bf(float f){
  unsigned int u = __float_as_uint(f);
  unsigned int r = (u + 0x7FFFu + ((u >> 16) & 1u)) >> 16;
  return (unsigned short)r;
}
// hardware RNE f32->bf16 (single cvt inst on gfx950)
__device__ inline unsigned short f2bf_hw(float f){
  return __builtin_bit_cast(unsigned short, __float2bfloat16(f));
}

// async global->LDS, 16B per lane, wave-uniform LDS base + lane*16
__device__ inline void gload16(const void* g, void* l){
  __builtin_amdgcn_global_load_lds(
      (const __attribute__((address_space(1))) void*)g,
      (__attribute__((address_space(3))) void*)l, 16, 0, 0);
}

// ---------------- kernel 1 (fused prep, vectorized): q|gates|k-norm|v-transpose ----------
__global__ __launch_bounds__(256) void k_prep(const float* __restrict__ q,
                                              const float* __restrict__ k,
                                              const float* __restrict__ v,
                                              const float* __restrict__ src,
                                              const float* __restrict__ dest,
                                              unsigned short* __restrict__ qb,
                                              unsigned short* __restrict__ knb,
                                              unsigned short* __restrict__ vT,
                                              float* __restrict__ sg,
                                              float* __restrict__ dg){
  __shared__ float tile[64][65];
  int bid = blockIdx.x;
  if (bid < 4096){
    int base = (bid*256 + threadIdx.x)*4;
    float4 qv = *(const float4*)(q + base);
    ushort4_t o;
    o[0] = f2bf_hw(qv.x*LOG2E); o[1] = f2bf_hw(qv.y*LOG2E);
    o[2] = f2bf_hw(qv.z*LOG2E); o[3] = f2bf_hw(qv.w*LOG2E);
    *(ushort4_t*)(qb + base) = o;
  } else if (bid < 4128){
    int e = ((bid - 4096)*256 + threadIdx.x)*4;     // over 32768 gate elems
    if (e < NHEADS*S_LEN){
      float4 dv = *(const float4*)(dest + e);
      float4 og;
      #pragma unroll
      for (int i = 0; i < 4; ++i){
        float x = (i==0)?dv.x:(i==1)?dv.y:(i==2)?dv.z:dv.w;
        float s = 1.f/(1.f + __expf(-x));
        float g = (s > 0.f) ? exp2f(log2f(s)*(1.f/3.f)) : 0.f;
        if (i==0) og.x=g; else if (i==1) og.y=g; else if (i==2) og.z=g; else og.w=g;
      }
      *(float4*)(dg + e) = og;
    } else {
      int e2 = e - NHEADS*S_LEN;
      float4 sv = *(const float4*)(src + e2);
      float4 og;
      #pragma unroll
      for (int i = 0; i < 4; ++i){
        float x = (i==0)?sv.x:(i==1)?sv.y:(i==2)?sv.z:sv.w;
        float s = 1.f/(1.f + __expf(-x));
        float g = (s > 0.f) ? exp2f(log2f(s)*(1.f/3.f)) : 0.f;
        if (i==0) og.x=g; else if (i==1) og.y=g; else if (i==2) og.z=g; else og.w=g;
      }
      *(float4*)(sg + e2) = og;
    }
  } else if (bid < 8224){
    int row  = (bid - 4128)*4 + (threadIdx.x >> 6);
    int lane = threadIdx.x & 63;
    size_t idx = (size_t)row*DH + lane;
    float x = k[idx];
    float ss = x*x;
    #pragma unroll
    for (int off = 32; off > 0; off >>= 1) ss += __shfl_xor(ss, off);
    float r = x / (sqrtf(ss) + 1e-6f);
    knb[idx] = f2bf(r);
  } else {
    int vb = bid - 8224;
    int bh = vb >> 4;
    int jt = vb & 15;
    int j0 = jt*64;
    int tid = threadIdx.x;
    int c = tid & 63, r4 = tid >> 6;
    const float* vbp = v + ((size_t)bh << 16);
    #pragma unroll
    for (int p = 0; p < 16; ++p){
      int j = p*4 + r4;
      tile[j][c] = vbp[(size_t)(j0 + j)*DH + c];
    }
    __syncthreads();
    unsigned short* ob = vT + ((size_t)bh << 16);
    #pragma unroll
    for (int p = 0; p < 16; ++p){
      int dd = p*4 + r4;
      ob[(size_t)dd*S_LEN + j0 + c] = f2bf_hw(tile[c][dd]);
    }
  }
}

// ---------------- kernel 2: T16 column sums of log2-decay (bf16 dot, LDS-staged) ---------
__global__ __launch_bounds__(256) void k_t16(const unsigned short* __restrict__ knh,
                                             const float* __restrict__ dg,
                                             const float* __restrict__ sg,
                                             float* __restrict__ T16){
  __shared__ unsigned short Ah[4096], Bh[4096];   // 16 KB
  int head = blockIdx.x / NTRI;
  int t    = blockIdx.x % NTRI;
  int ti = 0;
  while ((ti+1)*(ti+2)/2 <= t) ti++;
  int tj = t - ti*(ti+1)/2;
  int i0 = ti*64, j0 = tj*64;
  const unsigned short* Hp = knh + (size_t)head*S_LEN*DH;
  int w = threadIdx.x >> 6, lane = threadIdx.x & 63;
  int g16 = lane >> 4, l16 = lane & 15;

  // staging: wave w covers chunks w and w+4 of each 8KB array (1KB per gload16)
  int rsub = lane >> 3;
  int cisw = ((lane & 7) ^ rsub) * 8;
  int s0 = (w*8 + rsub)*64   + cisw;     // element offset in a 64x64 tile
  int s1 = ((w+4)*8 + rsub)*64 + cisw;
  int l0 = w*512, l1 = (w+4)*512;
  {
    const unsigned short* ha = Hp + (size_t)i0*DH;
    gload16(ha + s0, Ah + l0);  gload16(ha + s1, Ah + l1);
    if (ti != tj){
      const unsigned short* hb = Hp + (size_t)j0*DH;
      gload16(hb + s0, Bh + l0);  gload16(hb + s1, Bh + l1);
    }
  }
  __syncthreads();
  const unsigned short* bhp = (ti == tj) ? Ah : Bh;

  // swizzled fragment offsets: row = (group)*16 + l16, chunk (kk*4+g16)^(l16&7)
  int c0 = g16 ^ (l16 & 7);
  int e0 = l16*64 + c0*8;
  int e1 = l16*64 + (c0 ^ 4)*8;

  bf16x8 ah[2];
  ah[0] = *(const bf16x8*)(Ah + w*1024 + e0);
  ah[1] = *(const bf16x8*)(Ah + w*1024 + e1);

  f32x4 sc[4];
  #pragma unroll
  for (int n = 0; n < 4; ++n) sc[n] = (f32x4){0.f,0.f,0.f,0.f};
  #pragma unroll
  for (int n = 0; n < 4; ++n){
    bf16x8 bh0 = *(const bf16x8*)(bhp + n*1024 + e0);
    bf16x8 bh1 = *(const bf16x8*)(bhp + n*1024 + e1);
    sc[n] = __builtin_amdgcn_mfma_f32_16x16x32_bf16(ah[0], bh0, sc[n], 0, 0, 0);
    sc[n] = __builtin_amdgcn_mfma_f32_16x16x32_bf16(ah[1], bh1, sc[n], 0, 0, 0);
  }

  float dgv[4], sgv[4];
  #pragma unroll
  for (int r = 0; r < 4; ++r) dgv[r] = dg[head*S_LEN + i0 + w*16 + g16*4 + r];
  #pragma unroll
  for (int n = 0; n < 4; ++n) sgv[n] = sg[head*S_LEN + j0 + n*16 + l16];

  float tot[4];
  #pragma unroll
  for (int n = 0; n < 4; ++n){
    float s = 0.f;
    #pragma unroll
    for (int r = 0; r < 4; ++r){
      int gi = i0 + w*16 + g16*4 + r;
      int gj = j0 + n*16 + l16;
      float x = sc[n][r];
      float aff = (x > 0.f) ? exp2f(__log2f(x)*(2.f/3.f)) : 0.f;
      aff *= dgv[r]*sgv[n];
      float ld = __log2f(1.f - fminf(aff, 1.0f - 1e-6f));   // log2 domain
      s += (gi > gj) ? ld : 0.f;
    }
    tot[n] = s;
  }
  float wt[4];
  #pragma unroll
  for (int n = 0; n < 4; ++n){
    float t0 = __shfl(tot[n], l16);
    float t1 = __shfl(tot[n], 16 + l16);
    float t2 = __shfl(tot[n], 32 + l16);
    float t3 = __shfl(tot[n], 48 + l16);
    wt[n] = t0 + t1 + t2 + t3;
  }
  float sel = (g16 == 0) ? wt[0] : (g16 == 1) ? wt[1] : (g16 == 2) ? wt[2] : wt[3];
  T16[((size_t)head*64 + ti*4 + w)*S_LEN + j0 + g16*16 + l16] = sel;
}

// ---------------- kernel 3: exclusive scan over 16-row groups -> Cpre16 (4x parallel) ----
__global__ __launch_bounds__(256) void k_cpre16(const float* __restrict__ T16,
                                                float* __restrict__ Cpre16){
  __shared__ float tot[4][64];
  int head = blockIdx.x >> 4;
  int cb   = blockIdx.x & 15;
  int c    = threadIdx.x >> 6;          // gg-chunk (16 gg each)
  int ci   = threadIdx.x & 63;
  int col  = cb*64 + ci;
  int tjc  = cb;                        // col >> 6
  float loc[16];
  float run = 0.f;
  #pragma unroll
  for (int i = 0; i < 16; ++i){
    int gg = c*16 + i;
    loc[i] = run;
    if ((gg >> 2) >= tjc) run += T16[((size_t)head*64 + gg)*S_LEN + col];
  }
  tot[c][ci] = run;
  __syncthreads();
  float base = 0.f;
  #pragma unroll
  for (int cc = 0; cc < 3; ++cc)
    if (cc < c) base += tot[cc][ci];
  #pragma unroll
  for (int i = 0; i < 16; ++i){
    int gg = c*16 + i;
    Cpre16[((size_t)head*64 + gg)*S_LEN + col] = base + loc[i];
  }
}

// ---------------- kernel 4: fused flash attention (r17 + split BIAS load/compute) --------
// block = (kv-head, one 16-row i-block), 4 waves = 4 GQA q-heads. Monotone heavy-first
// decode. K/V double-buffered LDS via global_load_lds. Bias pipeline now SPLIT (r7
// pattern, first isolated test): K-row/gate/prefix loads for jt+1 issue at iteration TOP
// (covered by QK's ds_read+MFMA ~400cy); MFMA+elementwise compute runs after QK into
// double-buffered biasT. log2-domain softmax + THR=8 defer-rescale. Branch-free steady
// loop (last iter peeled), precomputed P-store ptrs.
// CLOSED families: launch_bounds(256,4) cap (r8,r12: spill), V-in-reg (r15: spill),
// 40KB/2-barrier (r18: occupancy unchanged, net -1%).
__global__ __launch_bounds__(256, 3) void k_attn(const unsigned short* __restrict__ qb,
                                              const unsigned short* __restrict__ knb,
                                              const unsigned short* __restrict__ vT,
                                              const float* __restrict__ Cpre16,
                                              const float* __restrict__ dg,
                                              const float* __restrict__ sg,
                                              float* __restrict__ out){
  __shared__ unsigned short kts[2][4096];   // [buf][64 j-rows][64 d] bf16, swizzled
  __shared__ unsigned short vts[2][4096];   // [buf][64 dd   ][64 j] bf16, swizzled
  __shared__ unsigned short plds[4096];     // [4 waves][16 rows][64 cols] bf16, wave-private
  __shared__ float biasT[2][64][20];        // col-major bias [buf][col][row], 80B stride

  int xcd   = blockIdx.x & 7;
  int inner = blockIdx.x >> 3;              // 0..127
  int kv    = (xcd << 1) | (inner & 1);     // 0..15
  int i16   = 63 - (inner >> 1);            // heavy first (r7 decode)
  int w     = threadIdx.x >> 6;
  int lane  = threadIdx.x & 63;
  int g16 = lane >> 4, l16 = lane & 15;
  int i0   = i16*16;
  int njt  = (i16 >> 2) + 1;
  int head = kv;
  int b = kv >> 3, gh = kv & 7;
  int bh = b*32 + gh*4 + w;

  const unsigned short* Kp = knb + (size_t)head*S_LEN*DH;
  const unsigned short* Vp = vT  + (size_t)head*DH*S_LEN;
  const unsigned short* Qp = qb  + ((size_t)bh*S_LEN + i0)*DH;
  const float*          Cp = Cpre16 + ((size_t)head*64 + i16)*S_LEN;

  // staging addressing: linear LDS dest + inverse-swizzled global src
  int rsub = lane >> 3;
  int cisw = ((lane & 7) ^ rsub) * 8;
  int kg0 = (w*8 + rsub)*64   + cisw;
  int kg1 = ((w+4)*8 + rsub)*64 + cisw;
  int vg0 = (w*8 + rsub)*1024 + cisw;
  int vg1 = ((w+4)*8 + rsub)*1024 + cisw;
  int kl0 = w*512;
  int kl1 = (w+4)*512;

  // fragment read offsets: row = n*16+l16, chunk (kk*4+g16)^(l16&7)
  int c0 = g16 ^ (l16 & 7);
  int e0 = l16*64 + c0*8;
  int e1 = l16*64 + (c0 ^ 4)*8;
  int hi = l16 >> 3, lo = l16 & 7;
  unsigned short* pw = plds + w*1024;

  // precomputed P-store pointers (loop-invariant; static indexing only)
  unsigned short* pp[16];
  #pragma unroll
  for (int n = 0; n < 4; ++n)
    #pragma unroll
    for (int r = 0; r < 4; ++r){
      int row = g16*4 + r;
      pp[n*4 + r] = pw + row*64 + (((2*n + hi) ^ (row & 7))*8) + lo;
    }

  // Q fragments (pre-scaled by log2e) + K A-fragments (i-rows) + row gates
  bf16x8 aq[2];
  aq[0] = *(const bf16x8*)(Qp + (size_t)l16*DH + g16*8);
  aq[1] = *(const bf16x8*)(Qp + (size_t)l16*DH + 32 + g16*8);
  bf16x8 ahK[2];
  {
    size_t ro = (size_t)(i0 + l16)*DH + g16*8;
    ahK[0] = *(const bf16x8*)(Kp + ro);
    ahK[1] = *(const bf16x8*)(Kp + ro + 32);
  }
  float dgw[4];
  #pragma unroll
  for (int r = 0; r < 4; ++r) dgw[r] = dg[head*S_LEN + i0 + g16*4 + r];

  auto STAGE = [&](int bb, int jtile){
    const unsigned short* ks = Kp + (size_t)jtile*(64*DH);
    const unsigned short* vs = Vp + (size_t)jtile*64;
    gload16(ks + kg0, &kts[bb][kl0]);
    gload16(ks + kg1, &kts[bb][kl1]);
    gload16(vs + vg0, &vts[bb][kl0]);
    gload16(vs + vg1, &vts[bb][kl1]);
  };

  // ---- split bias pipeline (r7 pattern; named scalar/vector state, no arrays) ----
  bf16x8 pbh0, pbh1;
  float  psg, pcp;
  int    pcolw;
  auto BIAS_LOAD = [&](int jt){
    pcolw = jt*64 + (w << 4) + l16;
    psg = sg[head*S_LEN + pcolw];
    pcp = Cp[pcolw];
    const unsigned short* hrow = Kp + (size_t)pcolw*DH;
    pbh0 = *(const bf16x8*)(hrow + g16*8);
    pbh1 = *(const bf16x8*)(hrow + 32 + g16*8);
  };
  auto BIAS_COMPUTE = [&](int buf){
    f32x4 bd = (f32x4){0.f,0.f,0.f,0.f};
    bd = __builtin_amdgcn_mfma_f32_16x16x32_bf16(ahK[0], pbh0, bd, 0, 0, 0);
    bd = __builtin_amdgcn_mfma_f32_16x16x32_bf16(ahK[1], pbh1, bd, 0, 0, 0);
    float pre[4];
    float s = 0.f;
    #pragma unroll
    for (int r = 0; r < 4; ++r){
      float x = bd[r];
      float aff = (x > 0.f) ? exp2f(__log2f(x)*(2.f/3.f)) : 0.f;
      aff *= dgw[r]*psg;
      float ld = __log2f(1.f - fminf(aff, 1.0f - 1e-6f));
      ld = ((i0 + g16*4 + r) > pcolw) ? ld : 0.f;
      pre[r] = s; s += ld;
    }
    float t0 = __shfl(s, l16);
    float t1 = __shfl(s, 16 + l16);
    float t2 = __shfl(s, 32 + l16);
    float offg = (g16 > 0 ? t0 : 0.f) + (g16 > 1 ? t1 : 0.f) + (g16 > 2 ? t2 : 0.f);
    f32x4 st;
    #pragma unroll
    for (int r = 0; r < 4; ++r) st[r] = pcp + offg + pre[r];
    *(f32x4*)&biasT[buf][(w << 4) + l16][g16*4] = st;   // one ds_write_b128
  };

  f32x4 oacc[4];
  float m[4], ssum[4];
  #pragma unroll
  for (int n = 0; n < 4; ++n) oacc[n] = (f32x4){0.f,0.f,0.f,0.f};
  #pragma unroll
  for (int r = 0; r < 4; ++r){ m[r] = NEG_INF; ssum[r] = 0.f; }

  // softmax + P-store + PV (shared by steady loop and peeled last iter)
  auto SM_PV = [&](f32x4* sc, const unsigned short* vcur){
    float mx[4];
    #pragma unroll
    for (int r = 0; r < 4; ++r)
      mx[r] = fmaxf(fmaxf(sc[0][r], sc[1][r]), fmaxf(sc[2][r], sc[3][r]));
    #pragma unroll
    for (int off = 8; off >= 1; off >>= 1)
      #pragma unroll
      for (int r = 0; r < 4; ++r)
        mx[r] = fmaxf(mx[r], __shfl_xor(mx[r], off));
    float dmax = fmaxf(fmaxf(mx[0]-m[0], mx[1]-m[1]), fmaxf(mx[2]-m[2], mx[3]-m[3]));
    if (__any(dmax > 8.f)){
      #pragma unroll
      for (int r = 0; r < 4; ++r){
        float mn = fmaxf(m[r], mx[r]);
        float scale = exp2f(m[r] - mn);
        m[r] = mn;
        ssum[r] *= scale;
        #pragma unroll
        for (int n = 0; n < 4; ++n) oacc[n][r] *= scale;
      }
    }
    #pragma unroll
    for (int n = 0; n < 4; ++n){
      #pragma unroll
      for (int r = 0; r < 4; ++r){
        float pv = exp2f(sc[n][r] - m[r]);     // raw v_exp_f32; bounded by 2^8
        ssum[r] += pv;
        *pp[n*4 + r] = f2bf_hw(pv);            // precomputed LDS address
      }
    }
    bf16x8 pa0 = *(const bf16x8*)(pw + e0);
    bf16x8 pa1 = *(const bf16x8*)(pw + e1);
    __builtin_amdgcn_s_setprio(1);
    #pragma unroll
    for (int n = 0; n < 4; ++n){
      bf16x8 bv = *(const bf16x8*)(vcur + n*1024 + e0);
      oacc[n] = __builtin_amdgcn_mfma_f32_16x16x32_bf16(pa0, bv, oacc[n], 0, 0, 0);
    }
    #pragma unroll
    for (int n = 0; n < 4; ++n){
      bf16x8 bv = *(const bf16x8*)(vcur + n*1024 + e1);
      oacc[n] = __builtin_amdgcn_mfma_f32_16x16x32_bf16(pa1, bv, oacc[n], 0, 0, 0);
    }
    __builtin_amdgcn_s_setprio(0);
  };

  // prologue: stage tile 0 + bias(0); one barrier makes both visible
  STAGE(0, 0);
  BIAS_LOAD(0);
  BIAS_COMPUTE(0);
  __syncthreads();

  int cur = 0, nb = 0;
  // ---- steady state: branch-free body (last iteration peeled) ----
  for (int jt = 0; jt < njt - 1; ++jt){
    const unsigned short* kcur = &kts[cur][0];
    const unsigned short* vcur = &vts[cur][0];

    STAGE(cur ^ 1, jt + 1);              // async, in flight across the whole iteration
    BIAS_LOAD(jt + 1);                   // issue bias K-row/gate loads; QK covers latency

    f32x4 sc[4];
    #pragma unroll
    for (int n = 0; n < 4; ++n) sc[n] = (f32x4){0.f,0.f,0.f,0.f};
    __builtin_amdgcn_s_setprio(1);
    #pragma unroll
    for (int n = 0; n < 4; ++n){
      bf16x8 bk0 = *(const bf16x8*)(kcur + n*1024 + e0);
      bf16x8 bk1 = *(const bf16x8*)(kcur + n*1024 + e1);
      sc[n] = __builtin_amdgcn_mfma_f32_16x16x32_bf16(aq[0], bk0, sc[n], 0, 0, 0);
      sc[n] = __builtin_amdgcn_mfma_f32_16x16x32_bf16(aq[1], bk1, sc[n], 0, 0, 0);
    }
    __builtin_amdgcn_s_setprio(0);

    BIAS_COMPUTE(nb ^ 1);                // loads already landed; off critical path

    #pragma unroll
    for (int n = 0; n < 4; ++n){
      f32x4 bvv = *(const f32x4*)&biasT[nb][n*16 + l16][g16*4];
      #pragma unroll
      for (int r = 0; r < 4; ++r) sc[n][r] += bvv[r];
    }

    SM_PV(sc, vcur);

    __syncthreads();                     // swaps kts/vts/biasT, drains STAGE vmcnt
    cur ^= 1; nb ^= 1;
  }

  // ---- peeled last iteration: masked bias add, no STAGE/BIAS, no trailing barrier ----
  {
    const unsigned short* kcur = &kts[cur][0];
    const unsigned short* vcur = &vts[cur][0];

    f32x4 sc[4];
    #pragma unroll
    for (int n = 0; n < 4; ++n) sc[n] = (f32x4){0.f,0.f,0.f,0.f};
    __builtin_amdgcn_s_setprio(1);
    #pragma unroll
    for (int n = 0; n < 4; ++n){
      bf16x8 bk0 = *(const bf16x8*)(kcur + n*1024 + e0);
      bf16x8 bk1 = *(const bf16x8*)(kcur + n*1024 + e1);
      sc[n] = __builtin_amdgcn_mfma_f32_16x16x32_bf16(aq[0], bk0, sc[n], 0, 0, 0);
      sc[n] = __builtin_amdgcn_mfma_f32_16x16x32_bf16(aq[1], bk1, sc[n], 0, 0, 0);
    }
    __builtin_amdgcn_s_setprio(0);

    int lim = (i16 & 3) << 4;
    #pragma unroll
    for (int n = 0; n < 4; ++n){
      f32x4 bvv = *(const f32x4*)&biasT[nb][n*16 + l16][g16*4];
      #pragma unroll
      for (int r = 0; r < 4; ++r){
        int row = g16*4 + r;
        int col = n*16 + l16;
        sc[n][r] = (col <= lim + row) ? (sc[n][r] + bvv[r]) : NEG_INF;
      }
    }

    SM_PV(sc, vcur);
  }

  // epilogue
  #pragma unroll
  for (int off = 8; off >= 1; off >>= 1)
    #pragma unroll
    for (int r = 0; r < 4; ++r) ssum[r] += __shfl_xor(ssum[r], off);
  float* Op = out + ((size_t)bh*S_LEN + i0)*DH;
  #pragma unroll
  for (int n = 0; n < 4; ++n)
    #pragma unroll
    for (int r = 0; r < 4; ++r)
      Op[(size_t)(g16*4 + r)*DH + n*16 + l16] = oacc[n][r] / ssum[r];
}

extern "C" void kernel_launch(void* const* d_in, const int* in_sizes, int n_in,
                              void* d_out, int out_size, void* d_ws, size_t ws_size,
                              hipStream_t stream){
  const float* q    = (const float*)d_in[0];
  const float* k    = (const float*)d_in[1];
  const float* v    = (const float*)d_in[2];
  const float* src  = (const float*)d_in[3];
  const float* dest = (const float*)d_in[4];
  float* out = (float*)d_out;

  char* w = (char*)d_ws;
  unsigned short* qb   = (unsigned short*)w;                          // 8 MB
  unsigned short* knb  = (unsigned short*)(w + (size_t)(8u  << 20));  // 2 MB
  unsigned short* vT   = (unsigned short*)(w + (size_t)(10u << 20));  // 2 MB
  float*          dg   = (float*)(w + (size_t)(12u << 20));           // 64 KB
  float*          sg   = (float*)(w + (size_t)(12u << 20) + 65536);   // 64 KB
  float*          T16  = (float*)(w + (size_t)(13u << 20));           // 4 MB
  float*          Cpre = (float*)(w + (size_t)(17u << 20));           // 4 MB

  k_prep   <<<dim3(8480), dim3(256), 0, stream>>>(q, k, v, src, dest, qb, knb, vT, sg, dg);
  k_t16    <<<dim3(NHEADS*NTRI), dim3(256), 0, stream>>>(knb, dg, sg, T16);
  k_cpre16 <<<dim3(NHEADS*16), dim3(256), 0, stream>>>(T16, Cpre);
  k_attn   <<<dim3(NB*NHKV*64), dim3(256), 0, stream>>>(qb, knb, vT, Cpre, dg, sg, out);
}

// Round 21
// 69.637 us; speedup vs baseline: 1.0231x; 1.0051x over previous
//
#include <hip/hip_runtime.h>
#include <hip/hip_bf16.h>
#include <math.h>

#define S_LEN 1024
#define DH 64
#define NB 2
#define NHQ 32
#define NHKV 8
#define NHEADS (NB*NHKV)      // 16 kv-head planes
#define NTILE 16              // S/64
#define NTRI 136              // 16*17/2 lower-tri tiles
#define NEG_INF -1e30f
#define LOG2E 1.44269504088896340736f

using bf16x8 = __attribute__((ext_vector_type(8))) __bf16;
using f32x4  = __attribute__((ext_vector_type(4))) float;
using ushort4_t = __attribute__((ext_vector_type(4))) unsigned short;

__device__ inline unsigned short f2bf(float f){
  unsigned int u = __float_as_uint(f);
  unsigned int r = (u + 0x7FFFu + ((u >> 16) & 1u)) >> 16;
  return (unsigned short)r;
}
// hardware RNE f32->bf16 (single cvt inst on gfx950)
__device__ inline unsigned short f2bf_hw(float f){
  return __builtin_bit_cast(unsigned short, __float2bfloat16(f));
}

// async global->LDS, 16B per lane, wave-uniform LDS base + lane*16
__device__ inline void gload16(const void* g, void* l){
  __builtin_amdgcn_global_load_lds(
      (const __attribute__((address_space(1))) void*)g,
      (__attribute__((address_space(3))) void*)l, 16, 0, 0);
}

// ---------------- kernel 1 (fused prep, vectorized): q|gates|k-norm|v-transpose ----------
__global__ __launch_bounds__(256) void k_prep(const float* __restrict__ q,
                                              const float* __restrict__ k,
                                              const float* __restrict__ v,
                                              const float* __restrict__ src,
                                              const float* __restrict__ dest,
                                              unsigned short* __restrict__ qb,
                                              unsigned short* __restrict__ knb,
                                              unsigned short* __restrict__ vT,
                                              float* __restrict__ sg,
                                              float* __restrict__ dg){
  __shared__ float tile[64][65];
  int bid = blockIdx.x;
  if (bid < 4096){
    int base = (bid*256 + threadIdx.x)*4;
    float4 qv = *(const float4*)(q + base);
    ushort4_t o;
    o[0] = f2bf_hw(qv.x*LOG2E); o[1] = f2bf_hw(qv.y*LOG2E);
    o[2] = f2bf_hw(qv.z*LOG2E); o[3] = f2bf_hw(qv.w*LOG2E);
    *(ushort4_t*)(qb + base) = o;
  } else if (bid < 4128){
    int e = ((bid - 4096)*256 + threadIdx.x)*4;     // over 32768 gate elems
    if (e < NHEADS*S_LEN){
      float4 dv = *(const float4*)(dest + e);
      float4 og;
      #pragma unroll
      for (int i = 0; i < 4; ++i){
        float x = (i==0)?dv.x:(i==1)?dv.y:(i==2)?dv.z:dv.w;
        float s = 1.f/(1.f + __expf(-x));
        float g = (s > 0.f) ? exp2f(log2f(s)*(1.f/3.f)) : 0.f;
        if (i==0) og.x=g; else if (i==1) og.y=g; else if (i==2) og.z=g; else og.w=g;
      }
      *(float4*)(dg + e) = og;
    } else {
      int e2 = e - NHEADS*S_LEN;
      float4 sv = *(const float4*)(src + e2);
      float4 og;
      #pragma unroll
      for (int i = 0; i < 4; ++i){
        float x = (i==0)?sv.x:(i==1)?sv.y:(i==2)?sv.z:sv.w;
        float s = 1.f/(1.f + __expf(-x));
        float g = (s > 0.f) ? exp2f(log2f(s)*(1.f/3.f)) : 0.f;
        if (i==0) og.x=g; else if (i==1) og.y=g; else if (i==2) og.z=g; else og.w=g;
      }
      *(float4*)(sg + e2) = og;
    }
  } else if (bid < 8224){
    int row  = (bid - 4128)*4 + (threadIdx.x >> 6);
    int lane = threadIdx.x & 63;
    size_t idx = (size_t)row*DH + lane;
    float x = k[idx];
    float ss = x*x;
    #pragma unroll
    for (int off = 32; off > 0; off >>= 1) ss += __shfl_xor(ss, off);
    float r = x / (sqrtf(ss) + 1e-6f);
    knb[idx] = f2bf(r);
  } else {
    int vb = bid - 8224;
    int bh = vb >> 4;
    int jt = vb & 15;
    int j0 = jt*64;
    int tid = threadIdx.x;
    int c = tid & 63, r4 = tid >> 6;
    const float* vbp = v + ((size_t)bh << 16);
    #pragma unroll
    for (int p = 0; p < 16; ++p){
      int j = p*4 + r4;
      tile[j][c] = vbp[(size_t)(j0 + j)*DH + c];
    }
    __syncthreads();
    unsigned short* ob = vT + ((size_t)bh << 16);
    #pragma unroll
    for (int p = 0; p < 16; ++p){
      int dd = p*4 + r4;
      ob[(size_t)dd*S_LEN + j0 + c] = f2bf_hw(tile[c][dd]);
    }
  }
}

// ---------------- kernel 2: T16 column sums of log2-decay (bf16 dot, LDS-staged) ---------
__global__ __launch_bounds__(256) void k_t16(const unsigned short* __restrict__ knh,
                                             const float* __restrict__ dg,
                                             const float* __restrict__ sg,
                                             float* __restrict__ T16){
  __shared__ unsigned short Ah[4096], Bh[4096];   // 16 KB
  int head = blockIdx.x / NTRI;
  int t    = blockIdx.x % NTRI;
  int ti = 0;
  while ((ti+1)*(ti+2)/2 <= t) ti++;
  int tj = t - ti*(ti+1)/2;
  int i0 = ti*64, j0 = tj*64;
  const unsigned short* Hp = knh + (size_t)head*S_LEN*DH;
  int w = threadIdx.x >> 6, lane = threadIdx.x & 63;
  int g16 = lane >> 4, l16 = lane & 15;

  // staging: wave w covers chunks w and w+4 of each 8KB array (1KB per gload16)
  int rsub = lane >> 3;
  int cisw = ((lane & 7) ^ rsub) * 8;
  int s0 = (w*8 + rsub)*64   + cisw;     // element offset in a 64x64 tile
  int s1 = ((w+4)*8 + rsub)*64 + cisw;
  int l0 = w*512, l1 = (w+4)*512;
  {
    const unsigned short* ha = Hp + (size_t)i0*DH;
    gload16(ha + s0, Ah + l0);  gload16(ha + s1, Ah + l1);
    if (ti != tj){
      const unsigned short* hb = Hp + (size_t)j0*DH;
      gload16(hb + s0, Bh + l0);  gload16(hb + s1, Bh + l1);
    }
  }
  __syncthreads();
  const unsigned short* bhp = (ti == tj) ? Ah : Bh;

  // swizzled fragment offsets: row = (group)*16 + l16, chunk (kk*4+g16)^(l16&7)
  int c0 = g16 ^ (l16 & 7);
  int e0 = l16*64 + c0*8;
  int e1 = l16*64 + (c0 ^ 4)*8;

  bf16x8 ah[2];
  ah[0] = *(const bf16x8*)(Ah + w*1024 + e0);
  ah[1] = *(const bf16x8*)(Ah + w*1024 + e1);

  f32x4 sc[4];
  #pragma unroll
  for (int n = 0; n < 4; ++n) sc[n] = (f32x4){0.f,0.f,0.f,0.f};
  #pragma unroll
  for (int n = 0; n < 4; ++n){
    bf16x8 bh0 = *(const bf16x8*)(bhp + n*1024 + e0);
    bf16x8 bh1 = *(const bf16x8*)(bhp + n*1024 + e1);
    sc[n] = __builtin_amdgcn_mfma_f32_16x16x32_bf16(ah[0], bh0, sc[n], 0, 0, 0);
    sc[n] = __builtin_amdgcn_mfma_f32_16x16x32_bf16(ah[1], bh1, sc[n], 0, 0, 0);
  }

  float dgv[4], sgv[4];
  #pragma unroll
  for (int r = 0; r < 4; ++r) dgv[r] = dg[head*S_LEN + i0 + w*16 + g16*4 + r];
  #pragma unroll
  for (int n = 0; n < 4; ++n) sgv[n] = sg[head*S_LEN + j0 + n*16 + l16];

  float tot[4];
  #pragma unroll
  for (int n = 0; n < 4; ++n){
    float s = 0.f;
    #pragma unroll
    for (int r = 0; r < 4; ++r){
      int gi = i0 + w*16 + g16*4 + r;
      int gj = j0 + n*16 + l16;
      float x = sc[n][r];
      float aff = (x > 0.f) ? exp2f(__log2f(x)*(2.f/3.f)) : 0.f;
      aff *= dgv[r]*sgv[n];
      float ld = __log2f(1.f - fminf(aff, 1.0f - 1e-6f));   // log2 domain
      s += (gi > gj) ? ld : 0.f;
    }
    tot[n] = s;
  }
  float wt[4];
  #pragma unroll
  for (int n = 0; n < 4; ++n){
    float t0 = __shfl(tot[n], l16);
    float t1 = __shfl(tot[n], 16 + l16);
    float t2 = __shfl(tot[n], 32 + l16);
    float t3 = __shfl(tot[n], 48 + l16);
    wt[n] = t0 + t1 + t2 + t3;
  }
  float sel = (g16 == 0) ? wt[0] : (g16 == 1) ? wt[1] : (g16 == 2) ? wt[2] : wt[3];
  T16[((size_t)head*64 + ti*4 + w)*S_LEN + j0 + g16*16 + l16] = sel;
}

// ---------------- kernel 3: exclusive scan over 16-row groups -> Cpre16 (4x parallel) ----
__global__ __launch_bounds__(256) void k_cpre16(const float* __restrict__ T16,
                                                float* __restrict__ Cpre16){
  __shared__ float tot[4][64];
  int head = blockIdx.x >> 4;
  int cb   = blockIdx.x & 15;
  int c    = threadIdx.x >> 6;          // gg-chunk (16 gg each)
  int ci   = threadIdx.x & 63;
  int col  = cb*64 + ci;
  int tjc  = cb;                        // col >> 6
  float loc[16];
  float run = 0.f;
  #pragma unroll
  for (int i = 0; i < 16; ++i){
    int gg = c*16 + i;
    loc[i] = run;
    if ((gg >> 2) >= tjc) run += T16[((size_t)head*64 + gg)*S_LEN + col];
  }
  tot[c][ci] = run;
  __syncthreads();
  float base = 0.f;
  #pragma unroll
  for (int cc = 0; cc < 3; ++cc)
    if (cc < c) base += tot[cc][ci];
  #pragma unroll
  for (int i = 0; i < 16; ++i){
    int gg = c*16 + i;
    Cpre16[((size_t)head*64 + gg)*S_LEN + col] = base + loc[i];
  }
}

// ---------------- kernel 4: fused flash attention (r20 + hoisted bias LDS reads) ---------
// block = (kv-head, one 16-row i-block), 4 waves = 4 GQA q-heads. Monotone heavy-first
// decode. K/V double-buffered LDS via global_load_lds. Bias pipeline split (r20):
// K-row/gate loads at top, MFMA+elementwise after QK. r21: the CURRENT-bias ds_read_b128s
// (data ready since last barrier) also hoisted to iteration top — QK covers their LDS
// latency. bvv[4] statically indexed (full unroll) -> registers, not scratch.
// log2-domain softmax + THR=8 defer-rescale. Branch-free steady loop (last iter peeled).
// CLOSED families: launch_bounds(256,4) cap (r8,r12: spill), V-in-reg (r15: spill),
// 40KB/2-barrier (r18: occupancy unchanged, net -1%).
__global__ __launch_bounds__(256, 3) void k_attn(const unsigned short* __restrict__ qb,
                                              const unsigned short* __restrict__ knb,
                                              const unsigned short* __restrict__ vT,
                                              const float* __restrict__ Cpre16,
                                              const float* __restrict__ dg,
                                              const float* __restrict__ sg,
                                              float* __restrict__ out){
  __shared__ unsigned short kts[2][4096];   // [buf][64 j-rows][64 d] bf16, swizzled
  __shared__ unsigned short vts[2][4096];   // [buf][64 dd   ][64 j] bf16, swizzled
  __shared__ unsigned short plds[4096];     // [4 waves][16 rows][64 cols] bf16, wave-private
  __shared__ float biasT[2][64][20];        // col-major bias [buf][col][row], 80B stride

  int xcd   = blockIdx.x & 7;
  int inner = blockIdx.x >> 3;              // 0..127
  int kv    = (xcd << 1) | (inner & 1);     // 0..15
  int i16   = 63 - (inner >> 1);            // heavy first (r7 decode)
  int w     = threadIdx.x >> 6;
  int lane  = threadIdx.x & 63;
  int g16 = lane >> 4, l16 = lane & 15;
  int i0   = i16*16;
  int njt  = (i16 >> 2) + 1;
  int head = kv;
  int b = kv >> 3, gh = kv & 7;
  int bh = b*32 + gh*4 + w;

  const unsigned short* Kp = knb + (size_t)head*S_LEN*DH;
  const unsigned short* Vp = vT  + (size_t)head*DH*S_LEN;
  const unsigned short* Qp = qb  + ((size_t)bh*S_LEN + i0)*DH;
  const float*          Cp = Cpre16 + ((size_t)head*64 + i16)*S_LEN;

  // staging addressing: linear LDS dest + inverse-swizzled global src
  int rsub = lane >> 3;
  int cisw = ((lane & 7) ^ rsub) * 8;
  int kg0 = (w*8 + rsub)*64   + cisw;
  int kg1 = ((w+4)*8 + rsub)*64 + cisw;
  int vg0 = (w*8 + rsub)*1024 + cisw;
  int vg1 = ((w+4)*8 + rsub)*1024 + cisw;
  int kl0 = w*512;
  int kl1 = (w+4)*512;

  // fragment read offsets: row = n*16+l16, chunk (kk*4+g16)^(l16&7)
  int c0 = g16 ^ (l16 & 7);
  int e0 = l16*64 + c0*8;
  int e1 = l16*64 + (c0 ^ 4)*8;
  int hi = l16 >> 3, lo = l16 & 7;
  unsigned short* pw = plds + w*1024;

  // precomputed P-store pointers (loop-invariant; static indexing only)
  unsigned short* pp[16];
  #pragma unroll
  for (int n = 0; n < 4; ++n)
    #pragma unroll
    for (int r = 0; r < 4; ++r){
      int row = g16*4 + r;
      pp[n*4 + r] = pw + row*64 + (((2*n + hi) ^ (row & 7))*8) + lo;
    }

  // Q fragments (pre-scaled by log2e) + K A-fragments (i-rows) + row gates
  bf16x8 aq[2];
  aq[0] = *(const bf16x8*)(Qp + (size_t)l16*DH + g16*8);
  aq[1] = *(const bf16x8*)(Qp + (size_t)l16*DH + 32 + g16*8);
  bf16x8 ahK[2];
  {
    size_t ro = (size_t)(i0 + l16)*DH + g16*8;
    ahK[0] = *(const bf16x8*)(Kp + ro);
    ahK[1] = *(const bf16x8*)(Kp + ro + 32);
  }
  float dgw[4];
  #pragma unroll
  for (int r = 0; r < 4; ++r) dgw[r] = dg[head*S_LEN + i0 + g16*4 + r];

  auto STAGE = [&](int bb, int jtile){
    const unsigned short* ks = Kp + (size_t)jtile*(64*DH);
    const unsigned short* vs = Vp + (size_t)jtile*64;
    gload16(ks + kg0, &kts[bb][kl0]);
    gload16(ks + kg1, &kts[bb][kl1]);
    gload16(vs + vg0, &vts[bb][kl0]);
    gload16(vs + vg1, &vts[bb][kl1]);
  };

  // ---- split bias pipeline (r20; named scalar/vector state, no address-taken arrays) ---
  bf16x8 pbh0, pbh1;
  float  psg, pcp;
  int    pcolw;
  auto BIAS_LOAD = [&](int jt){
    pcolw = jt*64 + (w << 4) + l16;
    psg = sg[head*S_LEN + pcolw];
    pcp = Cp[pcolw];
    const unsigned short* hrow = Kp + (size_t)pcolw*DH;
    pbh0 = *(const bf16x8*)(hrow + g16*8);
    pbh1 = *(const bf16x8*)(hrow + 32 + g16*8);
  };
  auto BIAS_COMPUTE = [&](int buf){
    f32x4 bd = (f32x4){0.f,0.f,0.f,0.f};
    bd = __builtin_amdgcn_mfma_f32_16x16x32_bf16(ahK[0], pbh0, bd, 0, 0, 0);
    bd = __builtin_amdgcn_mfma_f32_16x16x32_bf16(ahK[1], pbh1, bd, 0, 0, 0);
    float pre[4];
    float s = 0.f;
    #pragma unroll
    for (int r = 0; r < 4; ++r){
      float x = bd[r];
      float aff = (x > 0.f) ? exp2f(__log2f(x)*(2.f/3.f)) : 0.f;
      aff *= dgw[r]*psg;
      float ld = __log2f(1.f - fminf(aff, 1.0f - 1e-6f));
      ld = ((i0 + g16*4 + r) > pcolw) ? ld : 0.f;
      pre[r] = s; s += ld;
    }
    float t0 = __shfl(s, l16);
    float t1 = __shfl(s, 16 + l16);
    float t2 = __shfl(s, 32 + l16);
    float offg = (g16 > 0 ? t0 : 0.f) + (g16 > 1 ? t1 : 0.f) + (g16 > 2 ? t2 : 0.f);
    f32x4 st;
    #pragma unroll
    for (int r = 0; r < 4; ++r) st[r] = pcp + offg + pre[r];
    *(f32x4*)&biasT[buf][(w << 4) + l16][g16*4] = st;   // one ds_write_b128
  };

  f32x4 oacc[4];
  float m[4], ssum[4];
  #pragma unroll
  for (int n = 0; n < 4; ++n) oacc[n] = (f32x4){0.f,0.f,0.f,0.f};
  #pragma unroll
  for (int r = 0; r < 4; ++r){ m[r] = NEG_INF; ssum[r] = 0.f; }

  // softmax + P-store + PV (shared by steady loop and peeled last iter)
  auto SM_PV = [&](f32x4* sc, const unsigned short* vcur){
    float mx[4];
    #pragma unroll
    for (int r = 0; r < 4; ++r)
      mx[r] = fmaxf(fmaxf(sc[0][r], sc[1][r]), fmaxf(sc[2][r], sc[3][r]));
    #pragma unroll
    for (int off = 8; off >= 1; off >>= 1)
      #pragma unroll
      for (int r = 0; r < 4; ++r)
        mx[r] = fmaxf(mx[r], __shfl_xor(mx[r], off));
    float dmax = fmaxf(fmaxf(mx[0]-m[0], mx[1]-m[1]), fmaxf(mx[2]-m[2], mx[3]-m[3]));
    if (__any(dmax > 8.f)){
      #pragma unroll
      for (int r = 0; r < 4; ++r){
        float mn = fmaxf(m[r], mx[r]);
        float scale = exp2f(m[r] - mn);
        m[r] = mn;
        ssum[r] *= scale;
        #pragma unroll
        for (int n = 0; n < 4; ++n) oacc[n][r] *= scale;
      }
    }
    #pragma unroll
    for (int n = 0; n < 4; ++n){
      #pragma unroll
      for (int r = 0; r < 4; ++r){
        float pv = exp2f(sc[n][r] - m[r]);     // raw v_exp_f32; bounded by 2^8
        ssum[r] += pv;
        *pp[n*4 + r] = f2bf_hw(pv);            // precomputed LDS address
      }
    }
    bf16x8 pa0 = *(const bf16x8*)(pw + e0);
    bf16x8 pa1 = *(const bf16x8*)(pw + e1);
    __builtin_amdgcn_s_setprio(1);
    #pragma unroll
    for (int n = 0; n < 4; ++n){
      bf16x8 bv = *(const bf16x8*)(vcur + n*1024 + e0);
      oacc[n] = __builtin_amdgcn_mfma_f32_16x16x32_bf16(pa0, bv, oacc[n], 0, 0, 0);
    }
    #pragma unroll
    for (int n = 0; n < 4; ++n){
      bf16x8 bv = *(const bf16x8*)(vcur + n*1024 + e1);
      oacc[n] = __builtin_amdgcn_mfma_f32_16x16x32_bf16(pa1, bv, oacc[n], 0, 0, 0);
    }
    __builtin_amdgcn_s_setprio(0);
  };

  // prologue: stage tile 0 + bias(0); one barrier makes both visible
  STAGE(0, 0);
  BIAS_LOAD(0);
  BIAS_COMPUTE(0);
  __syncthreads();

  int cur = 0, nb = 0;
  // ---- steady state: branch-free body (last iteration peeled) ----
  for (int jt = 0; jt < njt - 1; ++jt){
    const unsigned short* kcur = &kts[cur][0];
    const unsigned short* vcur = &vts[cur][0];

    STAGE(cur ^ 1, jt + 1);              // async, in flight across the whole iteration
    BIAS_LOAD(jt + 1);                   // issue bias K-row/gate loads; QK covers latency

    // hoisted current-bias LDS reads (ready since last barrier; QK covers ds latency)
    f32x4 bvv[4];
    #pragma unroll
    for (int n = 0; n < 4; ++n)
      bvv[n] = *(const f32x4*)&biasT[nb][n*16 + l16][g16*4];

    f32x4 sc[4];
    #pragma unroll
    for (int n = 0; n < 4; ++n) sc[n] = (f32x4){0.f,0.f,0.f,0.f};
    __builtin_amdgcn_s_setprio(1);
    #pragma unroll
    for (int n = 0; n < 4; ++n){
      bf16x8 bk0 = *(const bf16x8*)(kcur + n*1024 + e0);
      bf16x8 bk1 = *(const bf16x8*)(kcur + n*1024 + e1);
      sc[n] = __builtin_amdgcn_mfma_f32_16x16x32_bf16(aq[0], bk0, sc[n], 0, 0, 0);
      sc[n] = __builtin_amdgcn_mfma_f32_16x16x32_bf16(aq[1], bk1, sc[n], 0, 0, 0);
    }
    __builtin_amdgcn_s_setprio(0);

    BIAS_COMPUTE(nb ^ 1);                // loads already landed; off critical path

    #pragma unroll
    for (int n = 0; n < 4; ++n)
      #pragma unroll
      for (int r = 0; r < 4; ++r) sc[n][r] += bvv[n][r];

    SM_PV(sc, vcur);

    __syncthreads();                     // swaps kts/vts/biasT, drains STAGE vmcnt
    cur ^= 1; nb ^= 1;
  }

  // ---- peeled last iteration: masked bias add, no STAGE/BIAS, no trailing barrier ----
  {
    const unsigned short* kcur = &kts[cur][0];
    const unsigned short* vcur = &vts[cur][0];

    f32x4 bvv[4];
    #pragma unroll
    for (int n = 0; n < 4; ++n)
      bvv[n] = *(const f32x4*)&biasT[nb][n*16 + l16][g16*4];

    f32x4 sc[4];
    #pragma unroll
    for (int n = 0; n < 4; ++n) sc[n] = (f32x4){0.f,0.f,0.f,0.f};
    __builtin_amdgcn_s_setprio(1);
    #pragma unroll
    for (int n = 0; n < 4; ++n){
      bf16x8 bk0 = *(const bf16x8*)(kcur + n*1024 + e0);
      bf16x8 bk1 = *(const bf16x8*)(kcur + n*1024 + e1);
      sc[n] = __builtin_amdgcn_mfma_f32_16x16x32_bf16(aq[0], bk0, sc[n], 0, 0, 0);
      sc[n] = __builtin_amdgcn_mfma_f32_16x16x32_bf16(aq[1], bk1, sc[n], 0, 0, 0);
    }
    __builtin_amdgcn_s_setprio(0);

    int lim = (i16 & 3) << 4;
    #pragma unroll
    for (int n = 0; n < 4; ++n){
      #pragma unroll
      for (int r = 0; r < 4; ++r){
        int row = g16*4 + r;
        int col = n*16 + l16;
        sc[n][r] = (col <= lim + row) ? (sc[n][r] + bvv[n][r]) : NEG_INF;
      }
    }

    SM_PV(sc, vcur);
  }

  // epilogue
  #pragma unroll
  for (int off = 8; off >= 1; off >>= 1)
    #pragma unroll
    for (int r = 0; r < 4; ++r) ssum[r] += __shfl_xor(ssum[r], off);
  float* Op = out + ((size_t)bh*S_LEN + i0)*DH;
  #pragma unroll
  for (int n = 0; n < 4; ++n)
    #pragma unroll
    for (int r = 0; r < 4; ++r)
      Op[(size_t)(g16*4 + r)*DH + n*16 + l16] = oacc[n][r] / ssum[r];
}

extern "C" void kernel_launch(void* const* d_in, const int* in_sizes, int n_in,
                              void* d_out, int out_size, void* d_ws, size_t ws_size,
                              hipStream_t stream){
  const float* q    = (const float*)d_in[0];
  const float* k    = (const float*)d_in[1];
  const float* v    = (const float*)d_in[2];
  const float* src  = (const float*)d_in[3];
  const float* dest = (const float*)d_in[4];
  float* out = (float*)d_out;

  char* w = (char*)d_ws;
  unsigned short* qb   = (unsigned short*)w;                          // 8 MB
  unsigned short* knb  = (unsigned short*)(w + (size_t)(8u  << 20));  // 2 MB
  unsigned short* vT   = (unsigned short*)(w + (size_t)(10u << 20));  // 2 MB
  float*          dg   = (float*)(w + (size_t)(12u << 20));           // 64 KB
  float*          sg   = (float*)(w + (size_t)(12u << 20) + 65536);   // 64 KB
  float*          T16  = (float*)(w + (size_t)(13u << 20));           // 4 MB
  float*          Cpre = (float*)(w + (size_t)(17u << 20));           // 4 MB

  k_prep   <<<dim3(8480), dim3(256), 0, stream>>>(q, k, v, src, dest, qb, knb, vT, sg, dg);
  k_t16    <<<dim3(NHEADS*NTRI), dim3(256), 0, stream>>>(knb, dg, sg, T16);
  k_cpre16 <<<dim3(NHEADS*16), dim3(256), 0, stream>>>(T16, Cpre);
  k_attn   <<<dim3(NB*NHKV*64), dim3(256), 0, stream>>>(qb, knb, vT, Cpre, dg, sg, out);
}